// Round 1
// baseline (1132.973 us; speedup 1.0000x reference)
//
#include <hip/hip_runtime.h>
#include <cstdint>
#include <cstddef>

#define DIM 128
#define BN_EPS 1e-5f

// ---------------- preprocessing ----------------

__global__ void deg_kernel(const int* __restrict__ ei, const float* __restrict__ ew,
                           float* __restrict__ deg, int E) {
  int e = blockIdx.x * blockDim.x + threadIdx.x;
  if (e < E) atomicAdd(&deg[ei[e]], ew[e]);
}

__global__ void dinv_kernel(float* __restrict__ deg, int N) {
  int i = blockIdx.x * blockDim.x + threadIdx.x;
  if (i < N) { float d = deg[i]; deg[i] = d > 0.f ? rsqrtf(fmaxf(d, 1e-30f)) : 0.f; }
}

__global__ void wl_hist_kernel(const int* __restrict__ ei, const float* __restrict__ ew,
                               const float* __restrict__ dinv, float* __restrict__ wL,
                               int* __restrict__ counts, int E) {
  int e = blockIdx.x * blockDim.x + threadIdx.x;
  if (e < E) {
    int r = ei[e], c = ei[E + e];
    wL[e] = -dinv[r] * ew[e] * dinv[c];
    atomicAdd(&counts[r], 1);
  }
}

__global__ __launch_bounds__(1024) void scan_kernel(const int* __restrict__ counts,
                                                    int* __restrict__ row_ptr, int n) {
  __shared__ int sdata[1024];
  __shared__ int carry_sh;
  if (threadIdx.x == 0) carry_sh = 0;
  __syncthreads();
  for (int base = 0; base < n; base += 1024) {
    int i = base + (int)threadIdx.x;
    int v = (i < n) ? counts[i] : 0;
    sdata[threadIdx.x] = v;
    __syncthreads();
    for (int off = 1; off < 1024; off <<= 1) {
      int t = (threadIdx.x >= (unsigned)off) ? sdata[threadIdx.x - off] : 0;
      __syncthreads();
      sdata[threadIdx.x] += t;
      __syncthreads();
    }
    int carry = carry_sh;
    int incl = sdata[threadIdx.x];
    if (i < n) row_ptr[i] = carry + incl - v;  // exclusive scan
    __syncthreads();
    if (threadIdx.x == 1023) carry_sh = carry + sdata[1023];
    __syncthreads();
  }
  if (threadIdx.x == 0) row_ptr[n] = carry_sh;
}

__global__ void scatter_kernel(const int* __restrict__ ei, const float* __restrict__ wL,
                               const int* __restrict__ row_ptr, int* __restrict__ cursor,
                               int* __restrict__ csr_col, float* __restrict__ csr_w, int E) {
  int e = blockIdx.x * blockDim.x + threadIdx.x;
  if (e < E) {
    int r = ei[e];
    int pos = row_ptr[r] + atomicAdd(&cursor[r], 1);
    csr_col[pos] = ei[E + e];
    csr_w[pos] = wL[e];
  }
}

// Wcat: rows 0-127 = W0 - W2 ; 128-255 = W1 ; 256-383 = 2*W2   (row=in, col=out)
__global__ void combine_weights_kernel(const float* __restrict__ W, float* __restrict__ Wcat) {
  int idx = blockIdx.x * blockDim.x + threadIdx.x;
  if (idx < DIM * DIM) {
    float w0 = W[idx], w1 = W[DIM * DIM + idx], w2 = W[2 * DIM * DIM + idx];
    Wcat[idx] = w0 - w2;
    Wcat[DIM * DIM + idx] = w1;
    Wcat[2 * DIM * DIM + idx] = 2.0f * w2;
  }
}

// ---------------- SpMM: Y = L_hat @ X  (CSR, one wave per row) ----------------

__global__ __launch_bounds__(256) void spmm_kernel(const int* __restrict__ row_ptr,
                                                   const int* __restrict__ csr_col,
                                                   const float* __restrict__ csr_w,
                                                   const float* __restrict__ X,
                                                   float* __restrict__ Y, int N) {
  int row = (blockIdx.x * blockDim.x + threadIdx.x) >> 6;
  int lane = threadIdx.x & 63;
  if (row >= N) return;
  int s = row_ptr[row], e = row_ptr[row + 1];
  float a0 = 0.f, a1 = 0.f;
  for (int j = s; j < e; ++j) {
    int c = csr_col[j];
    float w = csr_w[j];
    float2 v = *reinterpret_cast<const float2*>(X + (size_t)c * DIM + lane * 2);
    a0 += w * v.x;
    a1 += w * v.y;
  }
  *reinterpret_cast<float2*>(Y + (size_t)row * DIM + lane * 2) = make_float2(a0, a1);
}

// ---------------- layer GEMM: out = relu(X@Wcat[0:128] + S1@Wcat[128:256] + S2@Wcat[256:384]) ----------------
// BM=64, BN=128, BK=16, 256 threads, each computes 4x8.

__global__ __launch_bounds__(256) void gemm3_relu_kernel(const float* __restrict__ X,
                                                         const float* __restrict__ S1,
                                                         const float* __restrict__ S2,
                                                         const float* __restrict__ W,
                                                         float* __restrict__ out, int M) {
  __shared__ float As[16][64];
  __shared__ float Bs[16][128];
  int tid = threadIdx.x;
  int block_row = blockIdx.x * 64;
  int trow = tid >> 4, tcol = tid & 15;
  float acc[4][8] = {};
  const float* srcs[3] = {X, S1, S2};
  for (int seg = 0; seg < 3; ++seg) {
    const float* src = srcs[seg];
    for (int kk = 0; kk < DIM; kk += 16) {
      {
        int r = tid >> 2;
        int k4 = (tid & 3) * 4;
        int grow = block_row + r;
        float4 v = (grow < M)
                       ? *reinterpret_cast<const float4*>(src + (size_t)grow * DIM + kk + k4)
                       : make_float4(0.f, 0.f, 0.f, 0.f);
        As[k4 + 0][r] = v.x; As[k4 + 1][r] = v.y; As[k4 + 2][r] = v.z; As[k4 + 3][r] = v.w;
      }
      {
        int k = tid >> 5;
        int n4 = (tid & 31) * 4;
        const float* wp = W + (size_t)(seg * DIM + kk) * DIM;
        float4 v0 = *reinterpret_cast<const float4*>(wp + (size_t)k * DIM + n4);
        float4 v1 = *reinterpret_cast<const float4*>(wp + (size_t)(k + 8) * DIM + n4);
        *reinterpret_cast<float4*>(&Bs[k][n4]) = v0;
        *reinterpret_cast<float4*>(&Bs[k + 8][n4]) = v1;
      }
      __syncthreads();
#pragma unroll
      for (int k = 0; k < 16; ++k) {
        float4 a = *reinterpret_cast<const float4*>(&As[k][trow * 4]);
        float4 b0 = *reinterpret_cast<const float4*>(&Bs[k][tcol * 8]);
        float4 b1 = *reinterpret_cast<const float4*>(&Bs[k][tcol * 8 + 4]);
        float av[4] = {a.x, a.y, a.z, a.w};
        float bv[8] = {b0.x, b0.y, b0.z, b0.w, b1.x, b1.y, b1.z, b1.w};
#pragma unroll
        for (int i = 0; i < 4; ++i)
#pragma unroll
          for (int j = 0; j < 8; ++j) acc[i][j] += av[i] * bv[j];
      }
      __syncthreads();
    }
  }
#pragma unroll
  for (int i = 0; i < 4; ++i) {
    int grow = block_row + trow * 4 + i;
    if (grow < M) {
      float4 o0 = make_float4(fmaxf(acc[i][0], 0.f), fmaxf(acc[i][1], 0.f),
                              fmaxf(acc[i][2], 0.f), fmaxf(acc[i][3], 0.f));
      float4 o1 = make_float4(fmaxf(acc[i][4], 0.f), fmaxf(acc[i][5], 0.f),
                              fmaxf(acc[i][6], 0.f), fmaxf(acc[i][7], 0.f));
      *reinterpret_cast<float4*>(out + (size_t)grow * DIM + tcol * 8) = o0;
      *reinterpret_cast<float4*>(out + (size_t)grow * DIM + tcol * 8 + 4) = o1;
    }
  }
}

// ---------------- head GEMM: h = relu(X@Wc1 + bc1), accumulate column sum/sumsq ----------------
// M x 128 @ 128 x 256 ; grid.y = 2 selects 128-wide column half.

__global__ __launch_bounds__(256) void head_gemm_kernel(const float* __restrict__ X,
                                                        const float* __restrict__ Wc1,
                                                        const float* __restrict__ bc1,
                                                        float* __restrict__ h,
                                                        float* __restrict__ sums, int M) {
  __shared__ float As[16][64];
  __shared__ float Bs[16][128];
  int tid = threadIdx.x;
  int block_row = blockIdx.x * 64;
  int n0 = blockIdx.y * 128;
  int trow = tid >> 4, tcol = tid & 15;
  float acc[4][8] = {};
  for (int kk = 0; kk < DIM; kk += 16) {
    {
      int r = tid >> 2;
      int k4 = (tid & 3) * 4;
      int grow = block_row + r;
      float4 v = (grow < M)
                     ? *reinterpret_cast<const float4*>(X + (size_t)grow * DIM + kk + k4)
                     : make_float4(0.f, 0.f, 0.f, 0.f);
      As[k4 + 0][r] = v.x; As[k4 + 1][r] = v.y; As[k4 + 2][r] = v.z; As[k4 + 3][r] = v.w;
    }
    {
      int k = tid >> 5;
      int n4 = (tid & 31) * 4;
      const float* wp = Wc1 + (size_t)kk * 256 + n0;
      float4 v0 = *reinterpret_cast<const float4*>(wp + (size_t)k * 256 + n4);
      float4 v1 = *reinterpret_cast<const float4*>(wp + (size_t)(k + 8) * 256 + n4);
      *reinterpret_cast<float4*>(&Bs[k][n4]) = v0;
      *reinterpret_cast<float4*>(&Bs[k + 8][n4]) = v1;
    }
    __syncthreads();
#pragma unroll
    for (int k = 0; k < 16; ++k) {
      float4 a = *reinterpret_cast<const float4*>(&As[k][trow * 4]);
      float4 b0 = *reinterpret_cast<const float4*>(&Bs[k][tcol * 8]);
      float4 b1 = *reinterpret_cast<const float4*>(&Bs[k][tcol * 8 + 4]);
      float av[4] = {a.x, a.y, a.z, a.w};
      float bv[8] = {b0.x, b0.y, b0.z, b0.w, b1.x, b1.y, b1.z, b1.w};
#pragma unroll
      for (int i = 0; i < 4; ++i)
#pragma unroll
        for (int j = 0; j < 8; ++j) acc[i][j] += av[i] * bv[j];
    }
    __syncthreads();
  }
  // bias + relu + store; keep values for stats
  float bias[8];
#pragma unroll
  for (int j = 0; j < 8; ++j) bias[j] = bc1[n0 + tcol * 8 + j];
#pragma unroll
  for (int i = 0; i < 4; ++i) {
    int grow = block_row + trow * 4 + i;
    if (grow < M) {
#pragma unroll
      for (int j = 0; j < 8; ++j) acc[i][j] = fmaxf(acc[i][j] + bias[j], 0.f);
      *reinterpret_cast<float4*>(h + (size_t)grow * 256 + n0 + tcol * 8) =
          make_float4(acc[i][0], acc[i][1], acc[i][2], acc[i][3]);
      *reinterpret_cast<float4*>(h + (size_t)grow * 256 + n0 + tcol * 8 + 4) =
          make_float4(acc[i][4], acc[i][5], acc[i][6], acc[i][7]);
    } else {
#pragma unroll
      for (int j = 0; j < 8; ++j) acc[i][j] = 0.f;
    }
  }
  float psum[8], psq[8];
#pragma unroll
  for (int j = 0; j < 8; ++j) {
    psum[j] = acc[0][j] + acc[1][j] + acc[2][j] + acc[3][j];
    psq[j] = acc[0][j] * acc[0][j] + acc[1][j] * acc[1][j] + acc[2][j] * acc[2][j] +
             acc[3][j] * acc[3][j];
  }
  __syncthreads();
#pragma unroll
  for (int j = 0; j < 8; ++j) Bs[trow][tcol * 8 + j] = psum[j];
  __syncthreads();
  if (tid < 128) {
    float s = 0.f;
#pragma unroll
    for (int r = 0; r < 16; ++r) s += Bs[r][tid];
    atomicAdd(&sums[n0 + tid], s);
  }
  __syncthreads();
#pragma unroll
  for (int j = 0; j < 8; ++j) Bs[trow][tcol * 8 + j] = psq[j];
  __syncthreads();
  if (tid < 128) {
    float s = 0.f;
#pragma unroll
    for (int r = 0; r < 16; ++r) s += Bs[r][tid];
    atomicAdd(&sums[256 + n0 + tid], s);
  }
}

// ---------------- BN fold: Wc2_eff[c][j] = a[c]*Wc2[c][j]; bc2_eff = bc2 + b@Wc2 ----------------

__global__ __launch_bounds__(256) void bnfold_kernel(const float* __restrict__ sums,
                                                     const float* __restrict__ gamma,
                                                     const float* __restrict__ beta,
                                                     const float* __restrict__ Wc2,
                                                     const float* __restrict__ bc2,
                                                     float* __restrict__ W2e,
                                                     float* __restrict__ b2e, int M) {
  __shared__ float bsh[256];
  int c = threadIdx.x;
  float mean = sums[c] / (float)M;
  float var = sums[256 + c] / (float)M - mean * mean;
  float a = gamma[c] * rsqrtf(var + BN_EPS);
  float b = beta[c] - mean * a;
  for (int j = 0; j < 10; ++j) W2e[c * 10 + j] = a * Wc2[c * 10 + j];
  bsh[c] = b;
  __syncthreads();
  if (c < 10) {
    float s = bc2[c];
    for (int k = 0; k < 256; ++k) s += bsh[k] * Wc2[k * 10 + c];
    b2e[c] = s;
  }
}

// ---------------- final: logit = h @ W2e + b2e  (one wave per row) ----------------

__global__ __launch_bounds__(256) void final_kernel(const float* __restrict__ h,
                                                    const float* __restrict__ W2e,
                                                    const float* __restrict__ b2e,
                                                    float* __restrict__ out, int M) {
  __shared__ float Ws[2560];
  __shared__ float bs[10];
  for (int i = threadIdx.x; i < 2560; i += 256) Ws[i] = W2e[i];
  if (threadIdx.x < 10) bs[threadIdx.x] = b2e[threadIdx.x];
  __syncthreads();
  int row = (blockIdx.x * blockDim.x + threadIdx.x) >> 6;
  int lane = threadIdx.x & 63;
  if (row >= M) return;
  float4 hv = *reinterpret_cast<const float4*>(h + (size_t)row * 256 + lane * 4);
  float hvv[4] = {hv.x, hv.y, hv.z, hv.w};
  float p[10];
#pragma unroll
  for (int j = 0; j < 10; ++j) p[j] = 0.f;
#pragma unroll
  for (int t = 0; t < 4; ++t) {
    const float* wrow = &Ws[(lane * 4 + t) * 10];
#pragma unroll
    for (int j = 0; j < 10; ++j) p[j] += hvv[t] * wrow[j];
  }
#pragma unroll
  for (int off = 32; off > 0; off >>= 1)
#pragma unroll
    for (int j = 0; j < 10; ++j) p[j] += __shfl_down(p[j], off);
  if (lane == 0) {
#pragma unroll
    for (int j = 0; j < 10; ++j) out[(size_t)row * 10 + j] = p[j] + bs[j];
  }
}

__global__ void copy_kernel(const float* __restrict__ src, float* __restrict__ dst, int n) {
  int i = blockIdx.x * blockDim.x + threadIdx.x;
  if (i < n) dst[i] = src[i];
}

// ---------------- launch ----------------

extern "C" void kernel_launch(void* const* d_in, const int* in_sizes, int n_in,
                              void* d_out, int out_size, void* d_ws, size_t ws_size,
                              hipStream_t stream) {
  const float* features = (const float*)d_in[0];
  const int* ei = (const int*)d_in[1];
  const float* ew = (const float*)d_in[2];
  const float* W0 = (const float*)d_in[3];
  const float* W1 = (const float*)d_in[4];
  const float* W2 = (const float*)d_in[5];
  const float* Wc1 = (const float*)d_in[6];
  const float* bc1 = (const float*)d_in[7];
  const float* gamma = (const float*)d_in[8];
  const float* beta = (const float*)d_in[9];
  const float* Wc2 = (const float*)d_in[10];
  const float* bc2 = (const float*)d_in[11];
  float* out = (float*)d_out;

  const int N = in_sizes[0] / DIM;
  const int E = in_sizes[2];

  size_t off = 0;
  auto alloc = [&](size_t bytes) -> void* {
    void* p = (char*)d_ws + off;
    off += (bytes + 511) & ~(size_t)511;
    return p;
  };
  float* deg = (float*)alloc((size_t)N * 4);          // becomes dinv in place
  float* wL = (float*)alloc((size_t)E * 4);
  int* counts = (int*)alloc((size_t)N * 4);           // reused as cursor
  int* row_ptr = (int*)alloc((size_t)(N + 1) * 4);
  int* csr_col = (int*)alloc((size_t)E * 4);
  float* csr_w = (float*)alloc((size_t)E * 4);
  float* Wcat = (float*)alloc((size_t)3 * 384 * DIM * 4);  // 3 layers
  float* W2e = (float*)alloc(2560 * 4);
  float* b2e = (float*)alloc(16 * 4);
  float* sums = (float*)alloc(512 * 4);
  float* xbuf = (float*)alloc((size_t)N * DIM * 4);
  float* S1 = (float*)alloc((size_t)N * DIM * 4);
  float* S2 = (float*)alloc((size_t)N * DIM * 4);
  float* h = S1;  // aliases S1+S2 (N*256 floats), free at head time

  hipMemsetAsync(deg, 0, (size_t)N * 4, stream);
  hipMemsetAsync(counts, 0, (size_t)N * 4, stream);
  hipMemsetAsync(sums, 0, 512 * 4, stream);

  int eb = (E + 255) / 256;
  int nb = (N + 255) / 256;
  deg_kernel<<<eb, 256, 0, stream>>>(ei, ew, deg, E);
  dinv_kernel<<<nb, 256, 0, stream>>>(deg, N);
  wl_hist_kernel<<<eb, 256, 0, stream>>>(ei, ew, deg, wL, counts, E);
  scan_kernel<<<1, 1024, 0, stream>>>(counts, row_ptr, N);
  hipMemsetAsync(counts, 0, (size_t)N * 4, stream);
  scatter_kernel<<<eb, 256, 0, stream>>>(ei, wL, row_ptr, counts, csr_col, csr_w, E);

  for (int l = 0; l < 3; ++l) {
    const float* Wl = (l == 0) ? W0 : (l == 1) ? W1 : W2;
    combine_weights_kernel<<<(DIM * DIM + 255) / 256, 256, 0, stream>>>(Wl,
                                                                        Wcat + (size_t)l * 384 * DIM);
  }

  int spmm_blocks = (N + 3) / 4;  // 4 waves per block, 1 row per wave
  int gemm_blocks = (N + 63) / 64;
  for (int l = 0; l < 3; ++l) {
    const float* X = (l == 0) ? features : xbuf;
    spmm_kernel<<<spmm_blocks, 256, 0, stream>>>(row_ptr, csr_col, csr_w, X, S1, N);
    spmm_kernel<<<spmm_blocks, 256, 0, stream>>>(row_ptr, csr_col, csr_w, S1, S2, N);
    gemm3_relu_kernel<<<gemm_blocks, 256, 0, stream>>>(X, S1, S2, Wcat + (size_t)l * 384 * DIM,
                                                       xbuf, N);
  }

  dim3 hgrid(gemm_blocks, 2);
  head_gemm_kernel<<<hgrid, 256, 0, stream>>>(xbuf, Wc1, bc1, h, sums, N);
  bnfold_kernel<<<1, 256, 0, stream>>>(sums, gamma, beta, Wc2, bc2, W2e, b2e, N);
  final_kernel<<<(N + 3) / 4, 256, 0, stream>>>(h, W2e, b2e, out, N);
  copy_kernel<<<eb, 256, 0, stream>>>(ew, out + (size_t)N * 10, E);
}

// Round 2
// 799.546 us; speedup vs baseline: 1.4170x; 1.4170x over previous
//
#include <hip/hip_runtime.h>
#include <cstdint>
#include <cstddef>

#define DIM 128
#define BN_EPS 1e-5f

typedef short bf16x8 __attribute__((ext_vector_type(8)));
typedef float f32x4 __attribute__((ext_vector_type(4)));

__device__ __forceinline__ unsigned short f2bf(float f) {
  unsigned u = __float_as_uint(f);
  u = (u + 0x7fffu + ((u >> 16) & 1u)) >> 16;
  return (unsigned short)u;
}
__device__ __forceinline__ float bf2f(unsigned v) {  // low 16 bits
  return __uint_as_float(v << 16);
}

// ---------------- preprocessing ----------------

__global__ void deg_kernel(const int* __restrict__ ei, const float* __restrict__ ew,
                           float* __restrict__ deg, int E) {
  int e = blockIdx.x * blockDim.x + threadIdx.x;
  if (e < E) atomicAdd(&deg[ei[e]], ew[e]);
}

__global__ void dinv_kernel(float* __restrict__ deg, int N) {
  int i = blockIdx.x * blockDim.x + threadIdx.x;
  if (i < N) { float d = deg[i]; deg[i] = d > 0.f ? rsqrtf(fmaxf(d, 1e-30f)) : 0.f; }
}

__global__ void hist_kernel(const int* __restrict__ ei, int* __restrict__ counts, int E) {
  int e = blockIdx.x * blockDim.x + threadIdx.x;
  if (e < E) atomicAdd(&counts[ei[e]], 1);
}

// 3-phase scan: per-block scan + block totals, scan totals, add offsets.
__global__ __launch_bounds__(256) void scan_a_kernel(const int* __restrict__ counts,
                                                     int* __restrict__ row_ptr,
                                                     int* __restrict__ bsums, int n) {
  __shared__ int sd[256];
  int t = threadIdx.x;
  int i = blockIdx.x * 256 + t;
  int v = (i < n) ? counts[i] : 0;
  sd[t] = v;
  __syncthreads();
  for (int off = 1; off < 256; off <<= 1) {
    int x = (t >= off) ? sd[t - off] : 0;
    __syncthreads();
    sd[t] += x;
    __syncthreads();
  }
  if (i < n) row_ptr[i] = sd[t] - v;
  if (t == 255) bsums[blockIdx.x] = sd[255];
}

__global__ __launch_bounds__(256) void scan_b_kernel(int* __restrict__ bsums, int nb,
                                                     int* __restrict__ row_ptr, int n, int E) {
  __shared__ int sd[256];
  int t = threadIdx.x;
  int v = (t < nb) ? bsums[t] : 0;
  sd[t] = v;
  __syncthreads();
  for (int off = 1; off < 256; off <<= 1) {
    int x = (t >= off) ? sd[t - off] : 0;
    __syncthreads();
    sd[t] += x;
    __syncthreads();
  }
  if (t < nb) bsums[t] = sd[t] - v;  // exclusive offsets
  if (t == 0) row_ptr[n] = E;
}

__global__ __launch_bounds__(256) void scan_c_kernel(int* __restrict__ row_ptr,
                                                     const int* __restrict__ bsums, int n) {
  int i = blockIdx.x * 256 + threadIdx.x;
  if (i < n) row_ptr[i] += bsums[blockIdx.x];
}

__global__ void scatter_kernel(const int* __restrict__ ei, const float* __restrict__ ew,
                               const float* __restrict__ dinv, const int* __restrict__ row_ptr,
                               int* __restrict__ cursor, int2* __restrict__ cw, int E) {
  int e = blockIdx.x * blockDim.x + threadIdx.x;
  if (e < E) {
    int r = ei[e], c = ei[E + e];
    float w = -dinv[r] * ew[e] * dinv[c];
    int pos = row_ptr[r] + atomicAdd(&cursor[r], 1);
    cw[pos] = make_int2(c, __float_as_int(w));
  }
}

// ---------------- weight prep ----------------

// WcatT[o][k] bf16, k = seg*128 + i ; seg0 = W0-W2, seg1 = W1, seg2 = 2*W2
__global__ void combine_weightsT_kernel(const float* __restrict__ W,
                                        unsigned short* __restrict__ WcatT) {
  int idx = blockIdx.x * blockDim.x + threadIdx.x;
  if (idx < DIM * DIM) {
    int i = idx >> 7, o = idx & 127;
    float w0 = W[i * DIM + o];
    float w1 = W[DIM * DIM + i * DIM + o];
    float w2 = W[2 * DIM * DIM + i * DIM + o];
    WcatT[(size_t)o * 384 + i] = f2bf(w0 - w2);
    WcatT[(size_t)o * 384 + 128 + i] = f2bf(w1);
    WcatT[(size_t)o * 384 + 256 + i] = f2bf(2.0f * w2);
  }
}

// Wc1T[n][k] bf16 from Wc1 (128,256)
__global__ void wc1t_kernel(const float* __restrict__ Wc1, unsigned short* __restrict__ Wc1T) {
  int idx = blockIdx.x * blockDim.x + threadIdx.x;
  if (idx < 128 * 256) {
    int k = idx >> 8, n = idx & 255;
    Wc1T[(size_t)n * 128 + k] = f2bf(Wc1[(size_t)k * 256 + n]);
  }
}

__global__ void f2bf_kernel(const float* __restrict__ in, unsigned short* __restrict__ outp,
                            int n4) {
  int i = blockIdx.x * blockDim.x + threadIdx.x;
  if (i < n4) {
    float4 v = reinterpret_cast<const float4*>(in)[i];
    ushort4 o;
    o.x = f2bf(v.x); o.y = f2bf(v.y); o.z = f2bf(v.z); o.w = f2bf(v.w);
    reinterpret_cast<ushort4*>(outp)[i] = o;
  }
}

// ---------------- SpMM: Y = L_hat @ X (bf16 in/out, fp32 accum) ----------------

__global__ __launch_bounds__(256) void spmm_kernel(const int* __restrict__ row_ptr,
                                                   const int2* __restrict__ cw,
                                                   const unsigned short* __restrict__ X,
                                                   unsigned short* __restrict__ Y, int N) {
  int row = (blockIdx.x * blockDim.x + threadIdx.x) >> 6;
  int lane = threadIdx.x & 63;
  if (row >= N) return;
  int s = row_ptr[row], e = row_ptr[row + 1];
  float a0 = 0.f, a1 = 0.f, b0 = 0.f, b1 = 0.f;
  int j = s;
  for (; j + 1 < e; j += 2) {
    int2 c0 = cw[j], c1 = cw[j + 1];
    unsigned v0 = *reinterpret_cast<const unsigned*>(X + (size_t)c0.x * DIM + lane * 2);
    unsigned v1 = *reinterpret_cast<const unsigned*>(X + (size_t)c1.x * DIM + lane * 2);
    float w0 = __int_as_float(c0.y), w1 = __int_as_float(c1.y);
    a0 += w0 * bf2f(v0 & 0xffffu);
    a1 += w0 * bf2f(v0 >> 16);
    b0 += w1 * bf2f(v1 & 0xffffu);
    b1 += w1 * bf2f(v1 >> 16);
  }
  if (j < e) {
    int2 c0 = cw[j];
    unsigned v0 = *reinterpret_cast<const unsigned*>(X + (size_t)c0.x * DIM + lane * 2);
    float w0 = __int_as_float(c0.y);
    a0 += w0 * bf2f(v0 & 0xffffu);
    a1 += w0 * bf2f(v0 >> 16);
  }
  a0 += b0;
  a1 += b1;
  unsigned o = (unsigned)f2bf(a0) | ((unsigned)f2bf(a1) << 16);
  *reinterpret_cast<unsigned*>(Y + (size_t)row * DIM + lane * 2) = o;
}

// ---------------- layer GEMM (MFMA): out = relu(X@(W0-W2) + S1@W1 + S2@(2W2)) ----------------
// BM=128, BN=128, BK=32, 4 waves; wave w computes rows w*32..w*32+31 (2x8 16x16 frags).

__global__ __launch_bounds__(256) void gemm3_mfma_kernel(const unsigned short* __restrict__ X,
                                                         const unsigned short* __restrict__ S1,
                                                         const unsigned short* __restrict__ S2,
                                                         const unsigned short* __restrict__ BT,
                                                         unsigned short* __restrict__ out, int M) {
  __shared__ short As[128 * 40];
  __shared__ short Bs[128 * 40];
  int tid = threadIdx.x;
  int wv = tid >> 6, ln = tid & 63;
  int lg = ln >> 4, lr = ln & 15;
  int blockRow = blockIdx.x * 128;
  f32x4 acc[2][8];
#pragma unroll
  for (int m = 0; m < 2; ++m)
#pragma unroll
    for (int n = 0; n < 8; ++n) acc[m][n] = (f32x4){0.f, 0.f, 0.f, 0.f};
  const unsigned short* srcs[3] = {X, S1, S2};
  int srow = tid >> 1;
  int scol = (tid & 1) * 16;
  int arow = blockRow + srow;
  bool aok = arow < M;
  for (int seg = 0; seg < 3; ++seg) {
    const unsigned short* src = srcs[seg];
    for (int k0 = 0; k0 < DIM; k0 += 32) {
      float4 av0, av1;
      if (aok) {
        const float4* ap = reinterpret_cast<const float4*>(src + (size_t)arow * DIM + k0 + scol);
        av0 = ap[0];
        av1 = ap[1];
      } else {
        av0 = make_float4(0.f, 0.f, 0.f, 0.f);
        av1 = av0;
      }
      const float4* bp =
          reinterpret_cast<const float4*>(BT + (size_t)srow * 384 + seg * DIM + k0 + scol);
      float4 bv0 = bp[0], bv1 = bp[1];
      __syncthreads();
      *reinterpret_cast<float4*>(&As[srow * 40 + scol]) = av0;
      *reinterpret_cast<float4*>(&As[srow * 40 + scol + 8]) = av1;
      *reinterpret_cast<float4*>(&Bs[srow * 40 + scol]) = bv0;
      *reinterpret_cast<float4*>(&Bs[srow * 40 + scol + 8]) = bv1;
      __syncthreads();
      bf16x8 af[2], bf[8];
#pragma unroll
      for (int m = 0; m < 2; ++m)
        af[m] = *reinterpret_cast<const bf16x8*>(&As[(wv * 32 + m * 16 + lr) * 40 + lg * 8]);
#pragma unroll
      for (int n = 0; n < 8; ++n)
        bf[n] = *reinterpret_cast<const bf16x8*>(&Bs[(n * 16 + lr) * 40 + lg * 8]);
#pragma unroll
      for (int m = 0; m < 2; ++m)
#pragma unroll
        for (int n = 0; n < 8; ++n)
          acc[m][n] = __builtin_amdgcn_mfma_f32_16x16x32_bf16(af[m], bf[n], acc[m][n], 0, 0, 0);
    }
  }
#pragma unroll
  for (int m = 0; m < 2; ++m)
#pragma unroll
    for (int n = 0; n < 8; ++n) {
      int col = n * 16 + lr;
#pragma unroll
      for (int r = 0; r < 4; ++r) {
        int grow = blockRow + wv * 32 + m * 16 + lg * 4 + r;
        if (grow < M) out[(size_t)grow * DIM + col] = f2bf(fmaxf(acc[m][n][r], 0.f));
      }
    }
}

// ---------------- head GEMM (MFMA): h = relu(X@Wc1 + bc1), bf16 out ----------------

__global__ __launch_bounds__(256) void head_mfma_kernel(const unsigned short* __restrict__ X,
                                                        const unsigned short* __restrict__ BT,
                                                        const float* __restrict__ bc1,
                                                        unsigned short* __restrict__ h, int M) {
  __shared__ short As[128 * 40];
  __shared__ short Bs[128 * 40];
  int tid = threadIdx.x;
  int wv = tid >> 6, ln = tid & 63;
  int lg = ln >> 4, lr = ln & 15;
  int blockRow = blockIdx.x * 128;
  int n0 = blockIdx.y * 128;
  f32x4 acc[2][8];
#pragma unroll
  for (int m = 0; m < 2; ++m)
#pragma unroll
    for (int n = 0; n < 8; ++n) acc[m][n] = (f32x4){0.f, 0.f, 0.f, 0.f};
  int srow = tid >> 1;
  int scol = (tid & 1) * 16;
  int arow = blockRow + srow;
  bool aok = arow < M;
  for (int k0 = 0; k0 < DIM; k0 += 32) {
    float4 av0, av1;
    if (aok) {
      const float4* ap = reinterpret_cast<const float4*>(X + (size_t)arow * DIM + k0 + scol);
      av0 = ap[0];
      av1 = ap[1];
    } else {
      av0 = make_float4(0.f, 0.f, 0.f, 0.f);
      av1 = av0;
    }
    const float4* bp =
        reinterpret_cast<const float4*>(BT + (size_t)(n0 + srow) * DIM + k0 + scol);
    float4 bv0 = bp[0], bv1 = bp[1];
    __syncthreads();
    *reinterpret_cast<float4*>(&As[srow * 40 + scol]) = av0;
    *reinterpret_cast<float4*>(&As[srow * 40 + scol + 8]) = av1;
    *reinterpret_cast<float4*>(&Bs[srow * 40 + scol]) = bv0;
    *reinterpret_cast<float4*>(&Bs[srow * 40 + scol + 8]) = bv1;
    __syncthreads();
    bf16x8 af[2], bf[8];
#pragma unroll
    for (int m = 0; m < 2; ++m)
      af[m] = *reinterpret_cast<const bf16x8*>(&As[(wv * 32 + m * 16 + lr) * 40 + lg * 8]);
#pragma unroll
    for (int n = 0; n < 8; ++n)
      bf[n] = *reinterpret_cast<const bf16x8*>(&Bs[(n * 16 + lr) * 40 + lg * 8]);
#pragma unroll
    for (int m = 0; m < 2; ++m)
#pragma unroll
      for (int n = 0; n < 8; ++n)
        acc[m][n] = __builtin_amdgcn_mfma_f32_16x16x32_bf16(af[m], bf[n], acc[m][n], 0, 0, 0);
  }
#pragma unroll
  for (int m = 0; m < 2; ++m)
#pragma unroll
    for (int n = 0; n < 8; ++n) {
      int colg = n0 + n * 16 + lr;
      float bias = bc1[colg];
#pragma unroll
      for (int r = 0; r < 4; ++r) {
        int grow = blockRow + wv * 32 + m * 16 + lg * 4 + r;
        if (grow < M) h[(size_t)grow * 256 + colg] = f2bf(fmaxf(acc[m][n][r] + bias, 0.f));
      }
    }
}

// ---------------- column stats over h (bf16) ----------------

__global__ __launch_bounds__(256) void colsum_kernel(const unsigned short* __restrict__ h,
                                                     float* __restrict__ partial, int N) {
  int c = threadIdx.x;
  float s = 0.f, q = 0.f;
  for (int r = blockIdx.x; r < N; r += gridDim.x) {
    float v = bf2f((unsigned)h[(size_t)r * 256 + c]);
    s += v;
    q += v * v;
  }
  partial[(size_t)blockIdx.x * 512 + c] = s;
  partial[(size_t)blockIdx.x * 512 + 256 + c] = q;
}

__global__ __launch_bounds__(256) void bnfold_kernel(const float* __restrict__ partial,
                                                     const float* __restrict__ gamma,
                                                     const float* __restrict__ beta,
                                                     const float* __restrict__ Wc2,
                                                     const float* __restrict__ bc2,
                                                     float* __restrict__ W2e,
                                                     float* __restrict__ b2e, int M, int nblk) {
  __shared__ float bsh[256];
  int c = threadIdx.x;
  float s = 0.f, q = 0.f;
  for (int b = 0; b < nblk; ++b) {
    s += partial[(size_t)b * 512 + c];
    q += partial[(size_t)b * 512 + 256 + c];
  }
  float mean = s / (float)M;
  float var = q / (float)M - mean * mean;
  float a = gamma[c] * rsqrtf(var + BN_EPS);
  float b = beta[c] - mean * a;
  for (int j = 0; j < 10; ++j) W2e[c * 10 + j] = a * Wc2[c * 10 + j];
  bsh[c] = b;
  __syncthreads();
  if (c < 10) {
    float t = bc2[c];
    for (int k = 0; k < 256; ++k) t += bsh[k] * Wc2[k * 10 + c];
    b2e[c] = t;
  }
}

// ---------------- final: logit = h @ W2e + b2e (one wave per row) ----------------

__global__ __launch_bounds__(256) void final_kernel(const unsigned short* __restrict__ h,
                                                    const float* __restrict__ W2e,
                                                    const float* __restrict__ b2e,
                                                    float* __restrict__ out, int M) {
  __shared__ float Ws[2560];
  __shared__ float bs[10];
  for (int i = threadIdx.x; i < 2560; i += 256) Ws[i] = W2e[i];
  if (threadIdx.x < 10) bs[threadIdx.x] = b2e[threadIdx.x];
  __syncthreads();
  int row = (blockIdx.x * blockDim.x + threadIdx.x) >> 6;
  int lane = threadIdx.x & 63;
  if (row >= M) return;
  uint2 hv = *reinterpret_cast<const uint2*>(h + (size_t)row * 256 + lane * 4);
  float hvv[4] = {bf2f(hv.x & 0xffffu), bf2f(hv.x >> 16), bf2f(hv.y & 0xffffu), bf2f(hv.y >> 16)};
  float p[10];
#pragma unroll
  for (int j = 0; j < 10; ++j) p[j] = 0.f;
#pragma unroll
  for (int t = 0; t < 4; ++t) {
    const float* wrow = &Ws[(lane * 4 + t) * 10];
#pragma unroll
    for (int j = 0; j < 10; ++j) p[j] += hvv[t] * wrow[j];
  }
#pragma unroll
  for (int off = 32; off > 0; off >>= 1)
#pragma unroll
    for (int j = 0; j < 10; ++j) p[j] += __shfl_down(p[j], off);
  if (lane == 0) {
#pragma unroll
    for (int j = 0; j < 10; ++j) out[(size_t)row * 10 + j] = p[j] + bs[j];
  }
}

__global__ void copy4_kernel(const float* __restrict__ src, float* __restrict__ dst, int n) {
  int i = blockIdx.x * blockDim.x + threadIdx.x;
  int i4 = i * 4;
  if (i4 + 3 < n) {
    reinterpret_cast<float4*>(dst)[i] = reinterpret_cast<const float4*>(src)[i];
  } else {
    for (int k = i4; k < n; ++k) dst[k] = src[k];
  }
}

// ---------------- launch ----------------

extern "C" void kernel_launch(void* const* d_in, const int* in_sizes, int n_in,
                              void* d_out, int out_size, void* d_ws, size_t ws_size,
                              hipStream_t stream) {
  const float* features = (const float*)d_in[0];
  const int* ei = (const int*)d_in[1];
  const float* ew = (const float*)d_in[2];
  const float* W0 = (const float*)d_in[3];
  const float* W1 = (const float*)d_in[4];
  const float* W2 = (const float*)d_in[5];
  const float* Wc1 = (const float*)d_in[6];
  const float* bc1 = (const float*)d_in[7];
  const float* gamma = (const float*)d_in[8];
  const float* beta = (const float*)d_in[9];
  const float* Wc2 = (const float*)d_in[10];
  const float* bc2 = (const float*)d_in[11];
  float* out = (float*)d_out;

  const int N = in_sizes[0] / DIM;
  const int E = in_sizes[2];

  size_t off = 0;
  auto alloc = [&](size_t bytes) -> void* {
    void* p = (char*)d_ws + off;
    off += (bytes + 511) & ~(size_t)511;
    return p;
  };
  float* deg = (float*)alloc((size_t)N * 4);
  int* counts = (int*)alloc((size_t)N * 4);  // reused as cursor
  int* row_ptr = (int*)alloc((size_t)(N + 1) * 4);
  int* bsums = (int*)alloc(256 * 4);
  int2* cw = (int2*)alloc((size_t)E * 8);
  unsigned short* featbf = (unsigned short*)alloc((size_t)N * DIM * 2);
  unsigned short* xbuf = (unsigned short*)alloc((size_t)N * DIM * 2);
  unsigned short* S1 = (unsigned short*)alloc((size_t)N * DIM * 2);
  unsigned short* S2 = (unsigned short*)alloc((size_t)N * DIM * 2);
  unsigned short* h = (unsigned short*)alloc((size_t)N * 256 * 2);
  unsigned short* WcatT = (unsigned short*)alloc((size_t)3 * 128 * 384 * 2);
  unsigned short* Wc1T = (unsigned short*)alloc((size_t)256 * 128 * 2);
  float* W2e = (float*)alloc(2560 * 4);
  float* b2e = (float*)alloc(16 * 4);
  float* partial = (float*)alloc((size_t)64 * 512 * 4);

  hipMemsetAsync(deg, 0, (size_t)N * 4, stream);
  hipMemsetAsync(counts, 0, (size_t)N * 4, stream);

  int eb = (E + 255) / 256;
  int nb = (N + 255) / 256;
  int sb = (N + 255) / 256;  // scan blocks (256/elems)

  f2bf_kernel<<<(N * DIM / 4 + 255) / 256, 256, 0, stream>>>(features, featbf, N * DIM / 4);
  deg_kernel<<<eb, 256, 0, stream>>>(ei, ew, deg, E);
  dinv_kernel<<<nb, 256, 0, stream>>>(deg, N);
  hist_kernel<<<eb, 256, 0, stream>>>(ei, counts, E);
  scan_a_kernel<<<sb, 256, 0, stream>>>(counts, row_ptr, bsums, N);
  scan_b_kernel<<<1, 256, 0, stream>>>(bsums, sb, row_ptr, N, E);
  scan_c_kernel<<<sb, 256, 0, stream>>>(row_ptr, bsums, N);
  hipMemsetAsync(counts, 0, (size_t)N * 4, stream);
  scatter_kernel<<<eb, 256, 0, stream>>>(ei, ew, deg, row_ptr, counts, cw, E);

  for (int l = 0; l < 3; ++l) {
    const float* Wl = (l == 0) ? W0 : (l == 1) ? W1 : W2;
    combine_weightsT_kernel<<<(DIM * DIM + 255) / 256, 256, 0, stream>>>(
        Wl, WcatT + (size_t)l * 128 * 384);
  }
  wc1t_kernel<<<(128 * 256 + 255) / 256, 256, 0, stream>>>(Wc1, Wc1T);

  int spmm_blocks = (N + 3) / 4;
  int gemm_blocks = (N + 127) / 128;
  for (int l = 0; l < 3; ++l) {
    const unsigned short* X = (l == 0) ? featbf : xbuf;
    spmm_kernel<<<spmm_blocks, 256, 0, stream>>>(row_ptr, cw, X, S1, N);
    spmm_kernel<<<spmm_blocks, 256, 0, stream>>>(row_ptr, cw, S1, S2, N);
    gemm3_mfma_kernel<<<gemm_blocks, 256, 0, stream>>>(X, S1, S2, WcatT + (size_t)l * 128 * 384,
                                                       xbuf, N);
  }

  dim3 hgrid(gemm_blocks, 2);
  head_mfma_kernel<<<hgrid, 256, 0, stream>>>(xbuf, Wc1T, bc1, h, N);
  colsum_kernel<<<64, 256, 0, stream>>>(h, partial, N);
  bnfold_kernel<<<1, 256, 0, stream>>>(partial, gamma, beta, Wc2, bc2, W2e, b2e, N, 64);
  final_kernel<<<(N + 3) / 4, 256, 0, stream>>>(h, W2e, b2e, out, N);
  copy4_kernel<<<(E / 4 + 255) / 256, 256, 0, stream>>>(ew, out + (size_t)N * 10, E);
}

// Round 3
// 517.440 us; speedup vs baseline: 2.1896x; 1.5452x over previous
//
#include <hip/hip_runtime.h>
#include <cstdint>
#include <cstddef>

#define DIM 128
#define BN_EPS 1e-5f

typedef short bf16x8 __attribute__((ext_vector_type(8)));
typedef float f32x4 __attribute__((ext_vector_type(4)));

__device__ __forceinline__ unsigned short f2bf(float f) {
  unsigned u = __float_as_uint(f);
  u = (u + 0x7fffu + ((u >> 16) & 1u)) >> 16;
  return (unsigned short)u;
}
__device__ __forceinline__ float bf2f(unsigned v) {  // low 16 bits
  return __uint_as_float(v << 16);
}

// ---------------- preprocessing ----------------

__global__ void deg_hist_kernel(const int* __restrict__ ei, const float* __restrict__ ew,
                                float* __restrict__ deg, int* __restrict__ counts, int E) {
  int e = blockIdx.x * blockDim.x + threadIdx.x;
  if (e < E) {
    int r = ei[e];
    atomicAdd(&deg[r], ew[e]);
    atomicAdd(&counts[r], 1);
  }
}

__global__ void dinv_kernel(float* __restrict__ deg, int N) {
  int i = blockIdx.x * blockDim.x + threadIdx.x;
  if (i < N) { float d = deg[i]; deg[i] = d > 0.f ? rsqrtf(fmaxf(d, 1e-30f)) : 0.f; }
}

// 3-phase scan: per-block scan + block totals, scan totals, add offsets.
__global__ __launch_bounds__(256) void scan_a_kernel(const int* __restrict__ counts,
                                                     int* __restrict__ row_ptr,
                                                     int* __restrict__ bsums, int n) {
  __shared__ int sd[256];
  int t = threadIdx.x;
  int i = blockIdx.x * 256 + t;
  int v = (i < n) ? counts[i] : 0;
  sd[t] = v;
  __syncthreads();
  for (int off = 1; off < 256; off <<= 1) {
    int x = (t >= off) ? sd[t - off] : 0;
    __syncthreads();
    sd[t] += x;
    __syncthreads();
  }
  if (i < n) row_ptr[i] = sd[t] - v;
  if (t == 255) bsums[blockIdx.x] = sd[255];
}

__global__ __launch_bounds__(256) void scan_b_kernel(int* __restrict__ bsums, int nb,
                                                     int* __restrict__ row_ptr, int n, int E) {
  __shared__ int sd[256];
  int t = threadIdx.x;
  int v = (t < nb) ? bsums[t] : 0;
  sd[t] = v;
  __syncthreads();
  for (int off = 1; off < 256; off <<= 1) {
    int x = (t >= off) ? sd[t - off] : 0;
    __syncthreads();
    sd[t] += x;
    __syncthreads();
  }
  if (t < nb) bsums[t] = sd[t] - v;  // exclusive offsets
  if (t == 0) row_ptr[n] = E;
}

__global__ __launch_bounds__(256) void scan_c_kernel(int* __restrict__ row_ptr,
                                                     const int* __restrict__ bsums, int n) {
  int i = blockIdx.x * 256 + threadIdx.x;
  if (i < n) row_ptr[i] += bsums[blockIdx.x];
}

__global__ void scatter_kernel(const int* __restrict__ ei, const float* __restrict__ ew,
                               const float* __restrict__ dinv, const int* __restrict__ row_ptr,
                               int* __restrict__ cursor, int2* __restrict__ cw, int E) {
  int e = blockIdx.x * blockDim.x + threadIdx.x;
  if (e < E) {
    int r = ei[e], c = ei[E + e];
    float w = -dinv[r] * ew[e] * dinv[c];
    int pos = row_ptr[r] + atomicAdd(&cursor[r], 1);
    cw[pos] = make_int2(c, __float_as_int(w));
  }
}

// ---------------- weight prep ----------------

// WcatT[o][k] bf16, k = seg*128 + i ; seg0 = W0-W2, seg1 = W1, seg2 = 2*W2
__global__ void combine_weightsT_kernel(const float* __restrict__ W,
                                        unsigned short* __restrict__ WcatT) {
  int idx = blockIdx.x * blockDim.x + threadIdx.x;
  if (idx < DIM * DIM) {
    int i = idx >> 7, o = idx & 127;
    float w0 = W[i * DIM + o];
    float w1 = W[DIM * DIM + i * DIM + o];
    float w2 = W[2 * DIM * DIM + i * DIM + o];
    WcatT[(size_t)o * 384 + i] = f2bf(w0 - w2);
    WcatT[(size_t)o * 384 + 128 + i] = f2bf(w1);
    WcatT[(size_t)o * 384 + 256 + i] = f2bf(2.0f * w2);
  }
}

// Wc1T[n][k] bf16 from Wc1 (128,256)
__global__ void wc1t_kernel(const float* __restrict__ Wc1, unsigned short* __restrict__ Wc1T) {
  int idx = blockIdx.x * blockDim.x + threadIdx.x;
  if (idx < 128 * 256) {
    int k = idx >> 8, n = idx & 255;
    Wc1T[(size_t)n * 128 + k] = f2bf(Wc1[(size_t)k * 256 + n]);
  }
}

__global__ void f2bf_kernel(const float* __restrict__ in, unsigned short* __restrict__ outp,
                            int n4) {
  int i = blockIdx.x * blockDim.x + threadIdx.x;
  if (i < n4) {
    float4 v = reinterpret_cast<const float4*>(in)[i];
    ushort4 o;
    o.x = f2bf(v.x); o.y = f2bf(v.y); o.z = f2bf(v.z); o.w = f2bf(v.w);
    reinterpret_cast<ushort4*>(outp)[i] = o;
  }
}

// ---------------- SpMM: Y = L_hat @ X (bf16 in/out, fp32 accum, 4-way unroll) ----------------

__global__ __launch_bounds__(256) void spmm_kernel(const int* __restrict__ row_ptr,
                                                   const int2* __restrict__ cw,
                                                   const unsigned short* __restrict__ X,
                                                   unsigned short* __restrict__ Y, int N) {
  int row = (blockIdx.x * blockDim.x + threadIdx.x) >> 6;
  int lane = threadIdx.x & 63;
  if (row >= N) return;
  int s = row_ptr[row], e = row_ptr[row + 1];
  float a0 = 0.f, a1 = 0.f, b0 = 0.f, b1 = 0.f;
  float c0 = 0.f, c1 = 0.f, d0 = 0.f, d1 = 0.f;
  int j = s;
  for (; j + 3 < e; j += 4) {
    int2 e0 = cw[j], e1 = cw[j + 1], e2 = cw[j + 2], e3 = cw[j + 3];
    unsigned v0 = *reinterpret_cast<const unsigned*>(X + (size_t)e0.x * DIM + lane * 2);
    unsigned v1 = *reinterpret_cast<const unsigned*>(X + (size_t)e1.x * DIM + lane * 2);
    unsigned v2 = *reinterpret_cast<const unsigned*>(X + (size_t)e2.x * DIM + lane * 2);
    unsigned v3 = *reinterpret_cast<const unsigned*>(X + (size_t)e3.x * DIM + lane * 2);
    float w0 = __int_as_float(e0.y), w1 = __int_as_float(e1.y);
    float w2 = __int_as_float(e2.y), w3 = __int_as_float(e3.y);
    a0 += w0 * bf2f(v0 & 0xffffu); a1 += w0 * bf2f(v0 >> 16);
    b0 += w1 * bf2f(v1 & 0xffffu); b1 += w1 * bf2f(v1 >> 16);
    c0 += w2 * bf2f(v2 & 0xffffu); c1 += w2 * bf2f(v2 >> 16);
    d0 += w3 * bf2f(v3 & 0xffffu); d1 += w3 * bf2f(v3 >> 16);
  }
  for (; j < e; ++j) {
    int2 e0 = cw[j];
    unsigned v0 = *reinterpret_cast<const unsigned*>(X + (size_t)e0.x * DIM + lane * 2);
    float w0 = __int_as_float(e0.y);
    a0 += w0 * bf2f(v0 & 0xffffu);
    a1 += w0 * bf2f(v0 >> 16);
  }
  a0 += b0 + c0 + d0;
  a1 += b1 + c1 + d1;
  unsigned o = (unsigned)f2bf(a0) | ((unsigned)f2bf(a1) << 16);
  *reinterpret_cast<unsigned*>(Y + (size_t)row * DIM + lane * 2) = o;
}

// ---------------- layer GEMM (MFMA): out = relu(X@(W0-W2) + S1@W1 + S2@(2W2)) ----------------

__global__ __launch_bounds__(256) void gemm3_mfma_kernel(const unsigned short* __restrict__ X,
                                                         const unsigned short* __restrict__ S1,
                                                         const unsigned short* __restrict__ S2,
                                                         const unsigned short* __restrict__ BT,
                                                         unsigned short* __restrict__ out, int M) {
  __shared__ short As[128 * 40];
  __shared__ short Bs[128 * 40];
  int tid = threadIdx.x;
  int wv = tid >> 6, ln = tid & 63;
  int lg = ln >> 4, lr = ln & 15;
  int blockRow = blockIdx.x * 128;
  f32x4 acc[2][8];
#pragma unroll
  for (int m = 0; m < 2; ++m)
#pragma unroll
    for (int n = 0; n < 8; ++n) acc[m][n] = (f32x4){0.f, 0.f, 0.f, 0.f};
  const unsigned short* srcs[3] = {X, S1, S2};
  int srow = tid >> 1;
  int scol = (tid & 1) * 16;
  int arow = blockRow + srow;
  bool aok = arow < M;
  for (int seg = 0; seg < 3; ++seg) {
    const unsigned short* src = srcs[seg];
    for (int k0 = 0; k0 < DIM; k0 += 32) {
      float4 av0, av1;
      if (aok) {
        const float4* ap = reinterpret_cast<const float4*>(src + (size_t)arow * DIM + k0 + scol);
        av0 = ap[0];
        av1 = ap[1];
      } else {
        av0 = make_float4(0.f, 0.f, 0.f, 0.f);
        av1 = av0;
      }
      const float4* bp =
          reinterpret_cast<const float4*>(BT + (size_t)srow * 384 + seg * DIM + k0 + scol);
      float4 bv0 = bp[0], bv1 = bp[1];
      __syncthreads();
      *reinterpret_cast<float4*>(&As[srow * 40 + scol]) = av0;
      *reinterpret_cast<float4*>(&As[srow * 40 + scol + 8]) = av1;
      *reinterpret_cast<float4*>(&Bs[srow * 40 + scol]) = bv0;
      *reinterpret_cast<float4*>(&Bs[srow * 40 + scol + 8]) = bv1;
      __syncthreads();
      bf16x8 af[2], bf[8];
#pragma unroll
      for (int m = 0; m < 2; ++m)
        af[m] = *reinterpret_cast<const bf16x8*>(&As[(wv * 32 + m * 16 + lr) * 40 + lg * 8]);
#pragma unroll
      for (int n = 0; n < 8; ++n)
        bf[n] = *reinterpret_cast<const bf16x8*>(&Bs[(n * 16 + lr) * 40 + lg * 8]);
#pragma unroll
      for (int m = 0; m < 2; ++m)
#pragma unroll
        for (int n = 0; n < 8; ++n)
          acc[m][n] = __builtin_amdgcn_mfma_f32_16x16x32_bf16(af[m], bf[n], acc[m][n], 0, 0, 0);
    }
  }
#pragma unroll
  for (int m = 0; m < 2; ++m)
#pragma unroll
    for (int n = 0; n < 8; ++n) {
      int col = n * 16 + lr;
#pragma unroll
      for (int r = 0; r < 4; ++r) {
        int grow = blockRow + wv * 32 + m * 16 + lg * 4 + r;
        if (grow < M) out[(size_t)grow * DIM + col] = f2bf(fmaxf(acc[m][n][r], 0.f));
      }
    }
}

// ---------------- head GEMM (MFMA): h = relu(X@Wc1 + bc1), bf16 out + fused BN stats ----------------

__global__ __launch_bounds__(256) void head_mfma_kernel(const unsigned short* __restrict__ X,
                                                        const unsigned short* __restrict__ BT,
                                                        const float* __restrict__ bc1,
                                                        unsigned short* __restrict__ h,
                                                        float* __restrict__ sums, int M) {
  __shared__ short As[128 * 40];
  __shared__ short Bs[128 * 40];
  int tid = threadIdx.x;
  int wv = tid >> 6, ln = tid & 63;
  int lg = ln >> 4, lr = ln & 15;
  int blockRow = blockIdx.x * 128;
  int n0 = blockIdx.y * 128;
  f32x4 acc[2][8];
#pragma unroll
  for (int m = 0; m < 2; ++m)
#pragma unroll
    for (int n = 0; n < 8; ++n) acc[m][n] = (f32x4){0.f, 0.f, 0.f, 0.f};
  int srow = tid >> 1;
  int scol = (tid & 1) * 16;
  int arow = blockRow + srow;
  bool aok = arow < M;
  for (int k0 = 0; k0 < DIM; k0 += 32) {
    float4 av0, av1;
    if (aok) {
      const float4* ap = reinterpret_cast<const float4*>(X + (size_t)arow * DIM + k0 + scol);
      av0 = ap[0];
      av1 = ap[1];
    } else {
      av0 = make_float4(0.f, 0.f, 0.f, 0.f);
      av1 = av0;
    }
    const float4* bp =
        reinterpret_cast<const float4*>(BT + (size_t)(n0 + srow) * DIM + k0 + scol);
    float4 bv0 = bp[0], bv1 = bp[1];
    __syncthreads();
    *reinterpret_cast<float4*>(&As[srow * 40 + scol]) = av0;
    *reinterpret_cast<float4*>(&As[srow * 40 + scol + 8]) = av1;
    *reinterpret_cast<float4*>(&Bs[srow * 40 + scol]) = bv0;
    *reinterpret_cast<float4*>(&Bs[srow * 40 + scol + 8]) = bv1;
    __syncthreads();
    bf16x8 af[2], bf[8];
#pragma unroll
    for (int m = 0; m < 2; ++m)
      af[m] = *reinterpret_cast<const bf16x8*>(&As[(wv * 32 + m * 16 + lr) * 40 + lg * 8]);
#pragma unroll
    for (int n = 0; n < 8; ++n)
      bf[n] = *reinterpret_cast<const bf16x8*>(&Bs[(n * 16 + lr) * 40 + lg * 8]);
#pragma unroll
    for (int m = 0; m < 2; ++m)
#pragma unroll
      for (int n = 0; n < 8; ++n)
        acc[m][n] = __builtin_amdgcn_mfma_f32_16x16x32_bf16(af[m], bf[n], acc[m][n], 0, 0, 0);
  }
  float psum[8], psq[8];
#pragma unroll
  for (int n = 0; n < 8; ++n) { psum[n] = 0.f; psq[n] = 0.f; }
#pragma unroll
  for (int m = 0; m < 2; ++m)
#pragma unroll
    for (int n = 0; n < 8; ++n) {
      int colg = n0 + n * 16 + lr;
      float bias = bc1[colg];
#pragma unroll
      for (int r = 0; r < 4; ++r) {
        int grow = blockRow + wv * 32 + m * 16 + lg * 4 + r;
        if (grow < M) {
          float v = fmaxf(acc[m][n][r] + bias, 0.f);
          h[(size_t)grow * 256 + colg] = f2bf(v);
          psum[n] += v;
          psq[n] += v * v;
        }
      }
    }
  // block-level column reduction: 16 partial rows x 128 cols
  float* Rs = reinterpret_cast<float*>(As);
  int rid = wv * 4 + lg;
  __syncthreads();
#pragma unroll
  for (int n = 0; n < 8; ++n) Rs[rid * 128 + n * 16 + lr] = psum[n];
  __syncthreads();
  if (tid < 128) {
    float s = 0.f;
#pragma unroll
    for (int r = 0; r < 16; ++r) s += Rs[r * 128 + tid];
    atomicAdd(&sums[n0 + tid], s);
  }
  __syncthreads();
#pragma unroll
  for (int n = 0; n < 8; ++n) Rs[rid * 128 + n * 16 + lr] = psq[n];
  __syncthreads();
  if (tid < 128) {
    float s = 0.f;
#pragma unroll
    for (int r = 0; r < 16; ++r) s += Rs[r * 128 + tid];
    atomicAdd(&sums[256 + n0 + tid], s);
  }
}

__global__ __launch_bounds__(256) void bnfold_kernel(const float* __restrict__ sums,
                                                     const float* __restrict__ gamma,
                                                     const float* __restrict__ beta,
                                                     const float* __restrict__ Wc2,
                                                     const float* __restrict__ bc2,
                                                     float* __restrict__ W2e,
                                                     float* __restrict__ b2e, int M) {
  __shared__ float bsh[256];
  int c = threadIdx.x;
  float mean = sums[c] / (float)M;
  float var = sums[256 + c] / (float)M - mean * mean;
  float a = gamma[c] * rsqrtf(var + BN_EPS);
  float b = beta[c] - mean * a;
  for (int j = 0; j < 10; ++j) W2e[c * 10 + j] = a * Wc2[c * 10 + j];
  bsh[c] = b;
  __syncthreads();
  if (c < 10) {
    float t = bc2[c];
    for (int k = 0; k < 256; ++k) t += bsh[k] * Wc2[k * 10 + c];
    b2e[c] = t;
  }
}

// ---------------- final: logit = h @ W2e + b2e (one wave per row) ----------------

__global__ __launch_bounds__(256) void final_kernel(const unsigned short* __restrict__ h,
                                                    const float* __restrict__ W2e,
                                                    const float* __restrict__ b2e,
                                                    float* __restrict__ out, int M) {
  __shared__ float Ws[2560];
  __shared__ float bs[10];
  for (int i = threadIdx.x; i < 2560; i += 256) Ws[i] = W2e[i];
  if (threadIdx.x < 10) bs[threadIdx.x] = b2e[threadIdx.x];
  __syncthreads();
  int row = (blockIdx.x * blockDim.x + threadIdx.x) >> 6;
  int lane = threadIdx.x & 63;
  if (row >= M) return;
  uint2 hv = *reinterpret_cast<const uint2*>(h + (size_t)row * 256 + lane * 4);
  float hvv[4] = {bf2f(hv.x & 0xffffu), bf2f(hv.x >> 16), bf2f(hv.y & 0xffffu), bf2f(hv.y >> 16)};
  float p[10];
#pragma unroll
  for (int j = 0; j < 10; ++j) p[j] = 0.f;
#pragma unroll
  for (int t = 0; t < 4; ++t) {
    const float* wrow = &Ws[(lane * 4 + t) * 10];
#pragma unroll
    for (int j = 0; j < 10; ++j) p[j] += hvv[t] * wrow[j];
  }
#pragma unroll
  for (int off = 32; off > 0; off >>= 1)
#pragma unroll
    for (int j = 0; j < 10; ++j) p[j] += __shfl_down(p[j], off);
  if (lane == 0) {
#pragma unroll
    for (int j = 0; j < 10; ++j) out[(size_t)row * 10 + j] = p[j] + bs[j];
  }
}

__global__ void copy4_kernel(const float* __restrict__ src, float* __restrict__ dst, int n) {
  int i = blockIdx.x * blockDim.x + threadIdx.x;
  int i4 = i * 4;
  if (i4 + 3 < n) {
    reinterpret_cast<float4*>(dst)[i] = reinterpret_cast<const float4*>(src)[i];
  } else {
    for (int k = i4; k < n; ++k) dst[k] = src[k];
  }
}

// ---------------- launch ----------------

extern "C" void kernel_launch(void* const* d_in, const int* in_sizes, int n_in,
                              void* d_out, int out_size, void* d_ws, size_t ws_size,
                              hipStream_t stream) {
  const float* features = (const float*)d_in[0];
  const int* ei = (const int*)d_in[1];
  const float* ew = (const float*)d_in[2];
  const float* W0 = (const float*)d_in[3];
  const float* W1 = (const float*)d_in[4];
  const float* W2 = (const float*)d_in[5];
  const float* Wc1 = (const float*)d_in[6];
  const float* bc1 = (const float*)d_in[7];
  const float* gamma = (const float*)d_in[8];
  const float* beta = (const float*)d_in[9];
  const float* Wc2 = (const float*)d_in[10];
  const float* bc2 = (const float*)d_in[11];
  float* out = (float*)d_out;

  const int N = in_sizes[0] / DIM;
  const int E = in_sizes[2];

  size_t off = 0;
  auto alloc = [&](size_t bytes) -> void* {
    void* p = (char*)d_ws + off;
    off += (bytes + 511) & ~(size_t)511;
    return p;
  };
  float* deg = (float*)alloc((size_t)N * 4);
  int* counts = (int*)alloc((size_t)N * 4);  // reused as cursor
  int* row_ptr = (int*)alloc((size_t)(N + 1) * 4);
  int* bsums = (int*)alloc(256 * 4);
  int2* cw = (int2*)alloc((size_t)E * 8);
  unsigned short* featbf = (unsigned short*)alloc((size_t)N * DIM * 2);
  unsigned short* xbuf = (unsigned short*)alloc((size_t)N * DIM * 2);
  unsigned short* S1 = (unsigned short*)alloc((size_t)N * DIM * 2);
  unsigned short* S2 = (unsigned short*)alloc((size_t)N * DIM * 2);
  unsigned short* h = (unsigned short*)alloc((size_t)N * 256 * 2);
  unsigned short* WcatT = (unsigned short*)alloc((size_t)3 * 128 * 384 * 2);
  unsigned short* Wc1T = (unsigned short*)alloc((size_t)256 * 128 * 2);
  float* W2e = (float*)alloc(2560 * 4);
  float* b2e = (float*)alloc(16 * 4);
  float* sums = (float*)alloc(512 * 4);

  hipMemsetAsync(deg, 0, (size_t)N * 4, stream);
  hipMemsetAsync(counts, 0, (size_t)N * 4, stream);
  hipMemsetAsync(sums, 0, 512 * 4, stream);

  int eb = (E + 255) / 256;
  int nb = (N + 255) / 256;
  int sb = (N + 255) / 256;

  f2bf_kernel<<<(N * DIM / 4 + 255) / 256, 256, 0, stream>>>(features, featbf, N * DIM / 4);
  deg_hist_kernel<<<eb, 256, 0, stream>>>(ei, ew, deg, counts, E);
  dinv_kernel<<<nb, 256, 0, stream>>>(deg, N);
  scan_a_kernel<<<sb, 256, 0, stream>>>(counts, row_ptr, bsums, N);
  scan_b_kernel<<<1, 256, 0, stream>>>(bsums, sb, row_ptr, N, E);
  scan_c_kernel<<<sb, 256, 0, stream>>>(row_ptr, bsums, N);
  hipMemsetAsync(counts, 0, (size_t)N * 4, stream);
  scatter_kernel<<<eb, 256, 0, stream>>>(ei, ew, deg, row_ptr, counts, cw, E);

  for (int l = 0; l < 3; ++l) {
    const float* Wl = (l == 0) ? W0 : (l == 1) ? W1 : W2;
    combine_weightsT_kernel<<<(DIM * DIM + 255) / 256, 256, 0, stream>>>(
        Wl, WcatT + (size_t)l * 128 * 384);
  }
  wc1t_kernel<<<(128 * 256 + 255) / 256, 256, 0, stream>>>(Wc1, Wc1T);

  int spmm_blocks = (N + 3) / 4;
  int gemm_blocks = (N + 127) / 128;
  for (int l = 0; l < 3; ++l) {
    const unsigned short* X = (l == 0) ? featbf : xbuf;
    spmm_kernel<<<spmm_blocks, 256, 0, stream>>>(row_ptr, cw, X, S1, N);
    spmm_kernel<<<spmm_blocks, 256, 0, stream>>>(row_ptr, cw, S1, S2, N);
    gemm3_mfma_kernel<<<gemm_blocks, 256, 0, stream>>>(X, S1, S2, WcatT + (size_t)l * 128 * 384,
                                                       xbuf, N);
  }

  dim3 hgrid(gemm_blocks, 2);
  head_mfma_kernel<<<hgrid, 256, 0, stream>>>(xbuf, Wc1T, bc1, h, sums, N);
  bnfold_kernel<<<1, 256, 0, stream>>>(sums, gamma, beta, Wc2, bc2, W2e, b2e, N);
  final_kernel<<<(N + 3) / 4, 256, 0, stream>>>(h, W2e, b2e, out, N);
  copy4_kernel<<<(E / 4 + 255) / 256, 256, 0, stream>>>(ew, out + (size_t)N * 10, E);
}

// Round 4
// 498.064 us; speedup vs baseline: 2.2748x; 1.0389x over previous
//
#include <hip/hip_runtime.h>
#include <cstdint>
#include <cstddef>

#define DIM 128
#define BN_EPS 1e-5f
#define NS 8  // XCD shadow shards

typedef short bf16x8 __attribute__((ext_vector_type(8)));
typedef float f32x4 __attribute__((ext_vector_type(4)));

__device__ __forceinline__ unsigned short f2bf(float f) {
  unsigned u = __float_as_uint(f);
  u = (u + 0x7fffu + ((u >> 16) & 1u)) >> 16;
  return (unsigned short)u;
}
__device__ __forceinline__ float bf2f(unsigned v) {  // low 16 bits
  return __uint_as_float(v << 16);
}

// ---------------- preprocessing ----------------

// sharded: shard g = blockIdx & 7 (round-robin block->XCD => XCD-local atomics)
__global__ void deg_hist_kernel(const int* __restrict__ ei, const float* __restrict__ ew,
                                float* __restrict__ degS, int* __restrict__ countS, int E,
                                int N) {
  int e = blockIdx.x * blockDim.x + threadIdx.x;
  int g = blockIdx.x & (NS - 1);
  if (e < E) {
    int r = ei[e];
    atomicAdd(&degS[(size_t)g * N + r], ew[e]);
    atomicAdd(&countS[(size_t)g * N + r], 1);
  }
}

// deg = sum over shards; dinv in place
__global__ void reduce_dinv_kernel(const float* __restrict__ degS, float* __restrict__ dinv,
                                   int N) {
  int i = blockIdx.x * blockDim.x + threadIdx.x;
  if (i < N) {
    float d = 0.f;
#pragma unroll
    for (int g = 0; g < NS; ++g) d += degS[(size_t)g * N + i];
    dinv[i] = d > 0.f ? rsqrtf(fmaxf(d, 1e-30f)) : 0.f;
  }
}

// scan over 8N counts in (row-major, shard-minor) order -> off2[r*8+g]
__global__ __launch_bounds__(512) void scan_a_kernel(const int* __restrict__ countS,
                                                     int* __restrict__ off2,
                                                     int* __restrict__ bsums, int n8, int N) {
  __shared__ int sd[512];
  int t = threadIdx.x;
  int i = blockIdx.x * 512 + t;
  int v = 0;
  if (i < n8) {
    int g = i & (NS - 1), r = i >> 3;
    v = countS[(size_t)g * N + r];
  }
  sd[t] = v;
  __syncthreads();
  for (int off = 1; off < 512; off <<= 1) {
    int x = (t >= off) ? sd[t - off] : 0;
    __syncthreads();
    sd[t] += x;
    __syncthreads();
  }
  if (i < n8) off2[i] = sd[t] - v;
  if (t == 511) bsums[blockIdx.x] = sd[511];
}

__global__ __launch_bounds__(1024) void scan_b_kernel(int* __restrict__ bsums, int nb) {
  __shared__ int sd[1024];
  int t = threadIdx.x;
  int v = (t < nb) ? bsums[t] : 0;
  sd[t] = v;
  __syncthreads();
  for (int off = 1; off < 1024; off <<= 1) {
    int x = (t >= off) ? sd[t - off] : 0;
    __syncthreads();
    sd[t] += x;
    __syncthreads();
  }
  if (t < nb) bsums[t] = sd[t] - v;  // exclusive
}

__global__ __launch_bounds__(512) void scan_c_kernel(int* __restrict__ off2,
                                                     const int* __restrict__ bsums, int n8) {
  int i = blockIdx.x * 512 + threadIdx.x;
  if (i < n8) off2[i] += bsums[blockIdx.x];
}

__global__ void rowptr_kernel(const int* __restrict__ off2, int* __restrict__ row_ptr, int N,
                              int E) {
  int i = blockIdx.x * blockDim.x + threadIdx.x;
  if (i < N) row_ptr[i] = off2[i * NS];
  if (i == 0) row_ptr[N] = E;
}

__global__ void scatter_kernel(const int* __restrict__ ei, const float* __restrict__ ew,
                               const float* __restrict__ dinv, const int* __restrict__ off2,
                               int* __restrict__ cursorS, int2* __restrict__ cw, int E, int N) {
  int e = blockIdx.x * blockDim.x + threadIdx.x;
  int g = blockIdx.x & (NS - 1);
  if (e < E) {
    int r = ei[e], c = ei[E + e];
    float w = -dinv[r] * ew[e] * dinv[c];
    int pos = off2[r * NS + g] + atomicAdd(&cursorS[(size_t)g * N + r], 1);
    cw[pos] = make_int2(c, __float_as_int(w));
  }
}

// ---------------- weight prep ----------------

// WcatT[o][k] bf16, k = seg*128 + i ; seg0 = W0-W2, seg1 = W1, seg2 = 2*W2
__global__ void combine_weightsT_kernel(const float* __restrict__ W,
                                        unsigned short* __restrict__ WcatT) {
  int idx = blockIdx.x * blockDim.x + threadIdx.x;
  if (idx < DIM * DIM) {
    int i = idx >> 7, o = idx & 127;
    float w0 = W[i * DIM + o];
    float w1 = W[DIM * DIM + i * DIM + o];
    float w2 = W[2 * DIM * DIM + i * DIM + o];
    WcatT[(size_t)o * 384 + i] = f2bf(w0 - w2);
    WcatT[(size_t)o * 384 + 128 + i] = f2bf(w1);
    WcatT[(size_t)o * 384 + 256 + i] = f2bf(2.0f * w2);
  }
}

__global__ void wc1t_kernel(const float* __restrict__ Wc1, unsigned short* __restrict__ Wc1T) {
  int idx = blockIdx.x * blockDim.x + threadIdx.x;
  if (idx < 128 * 256) {
    int k = idx >> 8, n = idx & 255;
    Wc1T[(size_t)n * 128 + k] = f2bf(Wc1[(size_t)k * 256 + n]);
  }
}

__global__ void f2bf_kernel(const float* __restrict__ in, unsigned short* __restrict__ outp,
                            int n4) {
  int i = blockIdx.x * blockDim.x + threadIdx.x;
  if (i < n4) {
    float4 v = reinterpret_cast<const float4*>(in)[i];
    ushort4 o;
    o.x = f2bf(v.x); o.y = f2bf(v.y); o.z = f2bf(v.z); o.w = f2bf(v.w);
    reinterpret_cast<ushort4*>(outp)[i] = o;
  }
}

// ---------------- SpMM: Y = L_hat @ X (bf16 in/out, fp32 accum, 8-way MLP) ----------------

__global__ __launch_bounds__(256) void spmm_kernel(const int* __restrict__ row_ptr,
                                                   const int2* __restrict__ cw,
                                                   const unsigned short* __restrict__ X,
                                                   unsigned short* __restrict__ Y, int N) {
  int row = (blockIdx.x * blockDim.x + threadIdx.x) >> 6;
  int lane = threadIdx.x & 63;
  if (row >= N) return;
  int s = row_ptr[row], e = row_ptr[row + 1];
  float lo0 = 0.f, lo1 = 0.f, lo2 = 0.f, lo3 = 0.f, lo4 = 0.f, lo5 = 0.f, lo6 = 0.f, lo7 = 0.f;
  float hi0 = 0.f, hi1 = 0.f, hi2 = 0.f, hi3 = 0.f, hi4 = 0.f, hi5 = 0.f, hi6 = 0.f, hi7 = 0.f;
  int j = s;
  int lo2b = lane * 2;
  for (; j + 7 < e; j += 8) {
    int2 e0 = cw[j], e1 = cw[j + 1], e2 = cw[j + 2], e3 = cw[j + 3];
    int2 e4 = cw[j + 4], e5 = cw[j + 5], e6 = cw[j + 6], e7 = cw[j + 7];
    unsigned v0 = *reinterpret_cast<const unsigned*>(X + (size_t)e0.x * DIM + lo2b);
    unsigned v1 = *reinterpret_cast<const unsigned*>(X + (size_t)e1.x * DIM + lo2b);
    unsigned v2 = *reinterpret_cast<const unsigned*>(X + (size_t)e2.x * DIM + lo2b);
    unsigned v3 = *reinterpret_cast<const unsigned*>(X + (size_t)e3.x * DIM + lo2b);
    unsigned v4 = *reinterpret_cast<const unsigned*>(X + (size_t)e4.x * DIM + lo2b);
    unsigned v5 = *reinterpret_cast<const unsigned*>(X + (size_t)e5.x * DIM + lo2b);
    unsigned v6 = *reinterpret_cast<const unsigned*>(X + (size_t)e6.x * DIM + lo2b);
    unsigned v7 = *reinterpret_cast<const unsigned*>(X + (size_t)e7.x * DIM + lo2b);
    float w0 = __int_as_float(e0.y), w1 = __int_as_float(e1.y);
    float w2 = __int_as_float(e2.y), w3 = __int_as_float(e3.y);
    float w4 = __int_as_float(e4.y), w5 = __int_as_float(e5.y);
    float w6 = __int_as_float(e6.y), w7 = __int_as_float(e7.y);
    lo0 += w0 * bf2f(v0 & 0xffffu); hi0 += w0 * bf2f(v0 >> 16);
    lo1 += w1 * bf2f(v1 & 0xffffu); hi1 += w1 * bf2f(v1 >> 16);
    lo2 += w2 * bf2f(v2 & 0xffffu); hi2 += w2 * bf2f(v2 >> 16);
    lo3 += w3 * bf2f(v3 & 0xffffu); hi3 += w3 * bf2f(v3 >> 16);
    lo4 += w4 * bf2f(v4 & 0xffffu); hi4 += w4 * bf2f(v4 >> 16);
    lo5 += w5 * bf2f(v5 & 0xffffu); hi5 += w5 * bf2f(v5 >> 16);
    lo6 += w6 * bf2f(v6 & 0xffffu); hi6 += w6 * bf2f(v6 >> 16);
    lo7 += w7 * bf2f(v7 & 0xffffu); hi7 += w7 * bf2f(v7 >> 16);
  }
  for (; j + 1 < e; j += 2) {
    int2 e0 = cw[j], e1 = cw[j + 1];
    unsigned v0 = *reinterpret_cast<const unsigned*>(X + (size_t)e0.x * DIM + lo2b);
    unsigned v1 = *reinterpret_cast<const unsigned*>(X + (size_t)e1.x * DIM + lo2b);
    float w0 = __int_as_float(e0.y), w1 = __int_as_float(e1.y);
    lo0 += w0 * bf2f(v0 & 0xffffu); hi0 += w0 * bf2f(v0 >> 16);
    lo1 += w1 * bf2f(v1 & 0xffffu); hi1 += w1 * bf2f(v1 >> 16);
  }
  if (j < e) {
    int2 e0 = cw[j];
    unsigned v0 = *reinterpret_cast<const unsigned*>(X + (size_t)e0.x * DIM + lo2b);
    float w0 = __int_as_float(e0.y);
    lo0 += w0 * bf2f(v0 & 0xffffu);
    hi0 += w0 * bf2f(v0 >> 16);
  }
  float a0 = ((lo0 + lo1) + (lo2 + lo3)) + ((lo4 + lo5) + (lo6 + lo7));
  float a1 = ((hi0 + hi1) + (hi2 + hi3)) + ((hi4 + hi5) + (hi6 + hi7));
  unsigned o = (unsigned)f2bf(a0) | ((unsigned)f2bf(a1) << 16);
  *reinterpret_cast<unsigned*>(Y + (size_t)row * DIM + lo2b) = o;
}

// ---------------- layer GEMM (MFMA): out = relu(X@(W0-W2) + S1@W1 + S2@(2W2)) ----------------

__global__ __launch_bounds__(256) void gemm3_mfma_kernel(const unsigned short* __restrict__ X,
                                                         const unsigned short* __restrict__ S1,
                                                         const unsigned short* __restrict__ S2,
                                                         const unsigned short* __restrict__ BT,
                                                         unsigned short* __restrict__ out, int M) {
  __shared__ short As[128 * 40];
  __shared__ short Bs[128 * 40];
  int tid = threadIdx.x;
  int wv = tid >> 6, ln = tid & 63;
  int lg = ln >> 4, lr = ln & 15;
  int blockRow = blockIdx.x * 128;
  f32x4 acc[2][8];
#pragma unroll
  for (int m = 0; m < 2; ++m)
#pragma unroll
    for (int n = 0; n < 8; ++n) acc[m][n] = (f32x4){0.f, 0.f, 0.f, 0.f};
  const unsigned short* srcs[3] = {X, S1, S2};
  int srow = tid >> 1;
  int scol = (tid & 1) * 16;
  int arow = blockRow + srow;
  bool aok = arow < M;
  for (int seg = 0; seg < 3; ++seg) {
    const unsigned short* src = srcs[seg];
    for (int k0 = 0; k0 < DIM; k0 += 32) {
      float4 av0, av1;
      if (aok) {
        const float4* ap = reinterpret_cast<const float4*>(src + (size_t)arow * DIM + k0 + scol);
        av0 = ap[0];
        av1 = ap[1];
      } else {
        av0 = make_float4(0.f, 0.f, 0.f, 0.f);
        av1 = av0;
      }
      const float4* bp =
          reinterpret_cast<const float4*>(BT + (size_t)srow * 384 + seg * DIM + k0 + scol);
      float4 bv0 = bp[0], bv1 = bp[1];
      __syncthreads();
      *reinterpret_cast<float4*>(&As[srow * 40 + scol]) = av0;
      *reinterpret_cast<float4*>(&As[srow * 40 + scol + 8]) = av1;
      *reinterpret_cast<float4*>(&Bs[srow * 40 + scol]) = bv0;
      *reinterpret_cast<float4*>(&Bs[srow * 40 + scol + 8]) = bv1;
      __syncthreads();
      bf16x8 af[2], bf[8];
#pragma unroll
      for (int m = 0; m < 2; ++m)
        af[m] = *reinterpret_cast<const bf16x8*>(&As[(wv * 32 + m * 16 + lr) * 40 + lg * 8]);
#pragma unroll
      for (int n = 0; n < 8; ++n)
        bf[n] = *reinterpret_cast<const bf16x8*>(&Bs[(n * 16 + lr) * 40 + lg * 8]);
#pragma unroll
      for (int m = 0; m < 2; ++m)
#pragma unroll
        for (int n = 0; n < 8; ++n)
          acc[m][n] = __builtin_amdgcn_mfma_f32_16x16x32_bf16(af[m], bf[n], acc[m][n], 0, 0, 0);
    }
  }
#pragma unroll
  for (int m = 0; m < 2; ++m)
#pragma unroll
    for (int n = 0; n < 8; ++n) {
      int col = n * 16 + lr;
#pragma unroll
      for (int r = 0; r < 4; ++r) {
        int grow = blockRow + wv * 32 + m * 16 + lg * 4 + r;
        if (grow < M) out[(size_t)grow * DIM + col] = f2bf(fmaxf(acc[m][n][r], 0.f));
      }
    }
}

// ---------------- head GEMM (MFMA): h = relu(X@Wc1 + bc1), bf16 out + fused BN stats ----------------

__global__ __launch_bounds__(256) void head_mfma_kernel(const unsigned short* __restrict__ X,
                                                        const unsigned short* __restrict__ BT,
                                                        const float* __restrict__ bc1,
                                                        unsigned short* __restrict__ h,
                                                        float* __restrict__ sums, int M) {
  __shared__ short As[128 * 40];
  __shared__ short Bs[128 * 40];
  int tid = threadIdx.x;
  int wv = tid >> 6, ln = tid & 63;
  int lg = ln >> 4, lr = ln & 15;
  int blockRow = blockIdx.x * 128;
  int n0 = blockIdx.y * 128;
  f32x4 acc[2][8];
#pragma unroll
  for (int m = 0; m < 2; ++m)
#pragma unroll
    for (int n = 0; n < 8; ++n) acc[m][n] = (f32x4){0.f, 0.f, 0.f, 0.f};
  int srow = tid >> 1;
  int scol = (tid & 1) * 16;
  int arow = blockRow + srow;
  bool aok = arow < M;
  for (int k0 = 0; k0 < DIM; k0 += 32) {
    float4 av0, av1;
    if (aok) {
      const float4* ap = reinterpret_cast<const float4*>(X + (size_t)arow * DIM + k0 + scol);
      av0 = ap[0];
      av1 = ap[1];
    } else {
      av0 = make_float4(0.f, 0.f, 0.f, 0.f);
      av1 = av0;
    }
    const float4* bp =
        reinterpret_cast<const float4*>(BT + (size_t)(n0 + srow) * DIM + k0 + scol);
    float4 bv0 = bp[0], bv1 = bp[1];
    __syncthreads();
    *reinterpret_cast<float4*>(&As[srow * 40 + scol]) = av0;
    *reinterpret_cast<float4*>(&As[srow * 40 + scol + 8]) = av1;
    *reinterpret_cast<float4*>(&Bs[srow * 40 + scol]) = bv0;
    *reinterpret_cast<float4*>(&Bs[srow * 40 + scol + 8]) = bv1;
    __syncthreads();
    bf16x8 af[2], bf[8];
#pragma unroll
    for (int m = 0; m < 2; ++m)
      af[m] = *reinterpret_cast<const bf16x8*>(&As[(wv * 32 + m * 16 + lr) * 40 + lg * 8]);
#pragma unroll
    for (int n = 0; n < 8; ++n)
      bf[n] = *reinterpret_cast<const bf16x8*>(&Bs[(n * 16 + lr) * 40 + lg * 8]);
#pragma unroll
    for (int m = 0; m < 2; ++m)
#pragma unroll
      for (int n = 0; n < 8; ++n)
        acc[m][n] = __builtin_amdgcn_mfma_f32_16x16x32_bf16(af[m], bf[n], acc[m][n], 0, 0, 0);
  }
  float psum[8], psq[8];
#pragma unroll
  for (int n = 0; n < 8; ++n) { psum[n] = 0.f; psq[n] = 0.f; }
#pragma unroll
  for (int m = 0; m < 2; ++m)
#pragma unroll
    for (int n = 0; n < 8; ++n) {
      int colg = n0 + n * 16 + lr;
      float bias = bc1[colg];
#pragma unroll
      for (int r = 0; r < 4; ++r) {
        int grow = blockRow + wv * 32 + m * 16 + lg * 4 + r;
        if (grow < M) {
          float v = fmaxf(acc[m][n][r] + bias, 0.f);
          h[(size_t)grow * 256 + colg] = f2bf(v);
          psum[n] += v;
          psq[n] += v * v;
        }
      }
    }
  float* Rs = reinterpret_cast<float*>(As);
  int rid = wv * 4 + lg;
  __syncthreads();
#pragma unroll
  for (int n = 0; n < 8; ++n) Rs[rid * 128 + n * 16 + lr] = psum[n];
  __syncthreads();
  if (tid < 128) {
    float s = 0.f;
#pragma unroll
    for (int r = 0; r < 16; ++r) s += Rs[r * 128 + tid];
    atomicAdd(&sums[n0 + tid], s);
  }
  __syncthreads();
#pragma unroll
  for (int n = 0; n < 8; ++n) Rs[rid * 128 + n * 16 + lr] = psq[n];
  __syncthreads();
  if (tid < 128) {
    float s = 0.f;
#pragma unroll
    for (int r = 0; r < 16; ++r) s += Rs[r * 128 + tid];
    atomicAdd(&sums[256 + n0 + tid], s);
  }
}

__global__ __launch_bounds__(256) void bnfold_kernel(const float* __restrict__ sums,
                                                     const float* __restrict__ gamma,
                                                     const float* __restrict__ beta,
                                                     const float* __restrict__ Wc2,
                                                     const float* __restrict__ bc2,
                                                     float* __restrict__ W2e,
                                                     float* __restrict__ b2e, int M) {
  __shared__ float bsh[256];
  int c = threadIdx.x;
  float mean = sums[c] / (float)M;
  float var = sums[256 + c] / (float)M - mean * mean;
  float a = gamma[c] * rsqrtf(var + BN_EPS);
  float b = beta[c] - mean * a;
  for (int j = 0; j < 10; ++j) W2e[c * 10 + j] = a * Wc2[c * 10 + j];
  bsh[c] = b;
  __syncthreads();
  if (c < 10) {
    float t = bc2[c];
    for (int k = 0; k < 256; ++k) t += bsh[k] * Wc2[k * 10 + c];
    b2e[c] = t;
  }
}

// ---------------- final: logit = h @ W2e + b2e (one wave per row) ----------------

__global__ __launch_bounds__(256) void final_kernel(const unsigned short* __restrict__ h,
                                                    const float* __restrict__ W2e,
                                                    const float* __restrict__ b2e,
                                                    float* __restrict__ out, int M) {
  __shared__ float Ws[2560];
  __shared__ float bs[10];
  for (int i = threadIdx.x; i < 2560; i += 256) Ws[i] = W2e[i];
  if (threadIdx.x < 10) bs[threadIdx.x] = b2e[threadIdx.x];
  __syncthreads();
  int row = (blockIdx.x * blockDim.x + threadIdx.x) >> 6;
  int lane = threadIdx.x & 63;
  if (row >= M) return;
  uint2 hv = *reinterpret_cast<const uint2*>(h + (size_t)row * 256 + lane * 4);
  float hvv[4] = {bf2f(hv.x & 0xffffu), bf2f(hv.x >> 16), bf2f(hv.y & 0xffffu), bf2f(hv.y >> 16)};
  float p[10];
#pragma unroll
  for (int j = 0; j < 10; ++j) p[j] = 0.f;
#pragma unroll
  for (int t = 0; t < 4; ++t) {
    const float* wrow = &Ws[(lane * 4 + t) * 10];
#pragma unroll
    for (int j = 0; j < 10; ++j) p[j] += hvv[t] * wrow[j];
  }
#pragma unroll
  for (int off = 32; off > 0; off >>= 1)
#pragma unroll
    for (int j = 0; j < 10; ++j) p[j] += __shfl_down(p[j], off);
  if (lane == 0) {
#pragma unroll
    for (int j = 0; j < 10; ++j) out[(size_t)row * 10 + j] = p[j] + bs[j];
  }
}

__global__ void copy4_kernel(const float* __restrict__ src, float* __restrict__ dst, int n) {
  int i = blockIdx.x * blockDim.x + threadIdx.x;
  int i4 = i * 4;
  if (i4 + 3 < n) {
    reinterpret_cast<float4*>(dst)[i] = reinterpret_cast<const float4*>(src)[i];
  } else {
    for (int k = i4; k < n; ++k) dst[k] = src[k];
  }
}

// ---------------- launch ----------------

extern "C" void kernel_launch(void* const* d_in, const int* in_sizes, int n_in,
                              void* d_out, int out_size, void* d_ws, size_t ws_size,
                              hipStream_t stream) {
  const float* features = (const float*)d_in[0];
  const int* ei = (const int*)d_in[1];
  const float* ew = (const float*)d_in[2];
  const float* W0 = (const float*)d_in[3];
  const float* W1 = (const float*)d_in[4];
  const float* W2 = (const float*)d_in[5];
  const float* Wc1 = (const float*)d_in[6];
  const float* bc1 = (const float*)d_in[7];
  const float* gamma = (const float*)d_in[8];
  const float* beta = (const float*)d_in[9];
  const float* Wc2 = (const float*)d_in[10];
  const float* bc2 = (const float*)d_in[11];
  float* out = (float*)d_out;

  const int N = in_sizes[0] / DIM;
  const int E = in_sizes[2];
  const int n8 = N * NS;

  size_t off = 0;
  auto alloc = [&](size_t bytes) -> void* {
    void* p = (char*)d_ws + off;
    off += (bytes + 511) & ~(size_t)511;
    return p;
  };
  float* dinv = (float*)alloc((size_t)N * 4);
  float* degS = (float*)alloc((size_t)n8 * 4);
  int* countS = (int*)alloc((size_t)n8 * 4);
  int* cursorS = (int*)alloc((size_t)n8 * 4);
  int* off2 = (int*)alloc((size_t)(n8 + NS) * 4);
  int* bsums = (int*)alloc(1024 * 4);
  int* row_ptr = (int*)alloc((size_t)(N + 1) * 4);
  int2* cw = (int2*)alloc((size_t)E * 8);
  unsigned short* featbf = (unsigned short*)alloc((size_t)N * DIM * 2);
  unsigned short* xbuf = (unsigned short*)alloc((size_t)N * DIM * 2);
  unsigned short* S1 = (unsigned short*)alloc((size_t)N * DIM * 2);
  unsigned short* S2 = (unsigned short*)alloc((size_t)N * DIM * 2);
  unsigned short* h = (unsigned short*)alloc((size_t)N * 256 * 2);
  unsigned short* WcatT = (unsigned short*)alloc((size_t)3 * 128 * 384 * 2);
  unsigned short* Wc1T = (unsigned short*)alloc((size_t)256 * 128 * 2);
  float* W2e = (float*)alloc(2560 * 4);
  float* b2e = (float*)alloc(16 * 4);
  float* sums = (float*)alloc(512 * 4);

  hipMemsetAsync(degS, 0, (size_t)n8 * 4, stream);
  hipMemsetAsync(countS, 0, (size_t)n8 * 4, stream);
  hipMemsetAsync(cursorS, 0, (size_t)n8 * 4, stream);
  hipMemsetAsync(sums, 0, 512 * 4, stream);

  int eb = (E + 255) / 256;
  int nb = (N + 255) / 256;
  int sa_blocks = (n8 + 511) / 512;

  f2bf_kernel<<<(N * DIM / 4 + 255) / 256, 256, 0, stream>>>(features, featbf, N * DIM / 4);
  deg_hist_kernel<<<eb, 256, 0, stream>>>(ei, ew, degS, countS, E, N);
  reduce_dinv_kernel<<<nb, 256, 0, stream>>>(degS, dinv, N);
  scan_a_kernel<<<sa_blocks, 512, 0, stream>>>(countS, off2, bsums, n8, N);
  scan_b_kernel<<<1, 1024, 0, stream>>>(bsums, sa_blocks);
  scan_c_kernel<<<sa_blocks, 512, 0, stream>>>(off2, bsums, n8);
  rowptr_kernel<<<nb, 256, 0, stream>>>(off2, row_ptr, N, E);
  scatter_kernel<<<eb, 256, 0, stream>>>(ei, ew, dinv, off2, cursorS, cw, E, N);

  for (int l = 0; l < 3; ++l) {
    const float* Wl = (l == 0) ? W0 : (l == 1) ? W1 : W2;
    combine_weightsT_kernel<<<(DIM * DIM + 255) / 256, 256, 0, stream>>>(
        Wl, WcatT + (size_t)l * 128 * 384);
  }
  wc1t_kernel<<<(128 * 256 + 255) / 256, 256, 0, stream>>>(Wc1, Wc1T);

  int spmm_blocks = (N + 3) / 4;
  int gemm_blocks = (N + 127) / 128;
  for (int l = 0; l < 3; ++l) {
    const unsigned short* X = (l == 0) ? featbf : xbuf;
    spmm_kernel<<<spmm_blocks, 256, 0, stream>>>(row_ptr, cw, X, S1, N);
    spmm_kernel<<<spmm_blocks, 256, 0, stream>>>(row_ptr, cw, S1, S2, N);
    gemm3_mfma_kernel<<<gemm_blocks, 256, 0, stream>>>(X, S1, S2, WcatT + (size_t)l * 128 * 384,
                                                       xbuf, N);
  }

  dim3 hgrid(gemm_blocks, 2);
  head_mfma_kernel<<<hgrid, 256, 0, stream>>>(xbuf, Wc1T, bc1, h, sums, N);
  bnfold_kernel<<<1, 256, 0, stream>>>(sums, gamma, beta, Wc2, bc2, W2e, b2e, N);
  final_kernel<<<(N + 3) / 4, 256, 0, stream>>>(h, W2e, b2e, out, N);
  copy4_kernel<<<(E / 4 + 255) / 256, 256, 0, stream>>>(ew, out + (size_t)N * 10, E);
}

// Round 5
// 437.420 us; speedup vs baseline: 2.5901x; 1.1386x over previous
//
#include <hip/hip_runtime.h>
#include <cstdint>
#include <cstddef>

#define DIM 128
#define BN_EPS 1e-5f
#define NS 8  // shards (round-robin blockIdx -> XCD)
#define FIX_SCALE 16777216.0f  // 2^24

typedef short bf16x8 __attribute__((ext_vector_type(8)));
typedef float f32x4 __attribute__((ext_vector_type(4)));

__device__ __forceinline__ unsigned short f2bf(float f) {
  unsigned u = __float_as_uint(f);
  u = (u + 0x7fffu + ((u >> 16) & 1u)) >> 16;
  return (unsigned short)u;
}
__device__ __forceinline__ float bf2f(unsigned v) {  // low 16 bits
  return __uint_as_float(v << 16);
}

// ---------------- preprocessing ----------------

// One packed u64 atomic per edge: high32 = count, low32 = sum of fix24(ew).
// Returned old high word = this edge's rank within its (row,shard) segment.
__global__ void deg_hist_kernel(const int* __restrict__ ei, const float* __restrict__ ew,
                                unsigned long long* __restrict__ pck,
                                unsigned* __restrict__ eidx, int E, int N) {
  int e = blockIdx.x * blockDim.x + threadIdx.x;
  int g = blockIdx.x & (NS - 1);
  if (e < E) {
    int r = ei[e];
    unsigned fix = (unsigned)(ew[e] * FIX_SCALE + 0.5f);
    unsigned long long old =
        atomicAdd(&pck[(size_t)g * N + r], (1ull << 32) | (unsigned long long)fix);
    eidx[e] = (unsigned)(old >> 32);
  }
}

// deg = (sum over shards of low32) * 2^-24 ; dinv = rsqrt
__global__ void reduce_dinv_kernel(const unsigned long long* __restrict__ pck,
                                   float* __restrict__ dinv, int N) {
  int i = blockIdx.x * blockDim.x + threadIdx.x;
  if (i < N) {
    float d = 0.f;
#pragma unroll
    for (int g = 0; g < NS; ++g)
      d += (float)(unsigned)(pck[(size_t)g * N + i] & 0xffffffffull);
    d *= (1.0f / FIX_SCALE);
    dinv[i] = d > 0.f ? rsqrtf(fmaxf(d, 1e-30f)) : 0.f;
  }
}

// scan over 8N counts (row-major, shard-minor) -> off2[r*8+g]
__global__ __launch_bounds__(512) void scan_a_kernel(const unsigned long long* __restrict__ pck,
                                                     int* __restrict__ off2,
                                                     int* __restrict__ bsums, int n8, int N) {
  __shared__ int sd[512];
  int t = threadIdx.x;
  int i = blockIdx.x * 512 + t;
  int v = 0;
  if (i < n8) {
    int g = i & (NS - 1), r = i >> 3;
    v = (int)(pck[(size_t)g * N + r] >> 32);
  }
  sd[t] = v;
  __syncthreads();
  for (int off = 1; off < 512; off <<= 1) {
    int x = (t >= off) ? sd[t - off] : 0;
    __syncthreads();
    sd[t] += x;
    __syncthreads();
  }
  if (i < n8) off2[i] = sd[t] - v;
  if (t == 511) bsums[blockIdx.x] = sd[511];
}

__global__ __launch_bounds__(1024) void scan_b_kernel(int* __restrict__ bsums, int nb) {
  __shared__ int sd[1024];
  int t = threadIdx.x;
  int v = (t < nb) ? bsums[t] : 0;
  sd[t] = v;
  __syncthreads();
  for (int off = 1; off < 1024; off <<= 1) {
    int x = (t >= off) ? sd[t - off] : 0;
    __syncthreads();
    sd[t] += x;
    __syncthreads();
  }
  if (t < nb) bsums[t] = sd[t] - v;  // exclusive
}

// add block offsets; also emit row_ptr (every 8th element) and row_ptr[N]=E
__global__ __launch_bounds__(512) void scan_c_kernel(int* __restrict__ off2,
                                                     const int* __restrict__ bsums,
                                                     int* __restrict__ row_ptr, int n8, int N,
                                                     int E) {
  int i = blockIdx.x * 512 + threadIdx.x;
  if (i < n8) {
    int v = off2[i] + bsums[blockIdx.x];
    off2[i] = v;
    if ((i & (NS - 1)) == 0) row_ptr[i >> 3] = v;
  }
  if (blockIdx.x == 0 && threadIdx.x == 0) row_ptr[N] = E;
}

// atomic-free scatter: pos = off2[r*8+g] + eidx[e]  (same grid/g mapping as deg_hist)
__global__ void scatter_kernel(const int* __restrict__ ei, const float* __restrict__ ew,
                               const float* __restrict__ dinv, const int* __restrict__ off2,
                               const unsigned* __restrict__ eidx, int2* __restrict__ cw, int E,
                               int N) {
  int e = blockIdx.x * blockDim.x + threadIdx.x;
  int g = blockIdx.x & (NS - 1);
  if (e < E) {
    int r = ei[e], c = ei[E + e];
    float w = -dinv[r] * ew[e] * dinv[c];
    int pos = off2[r * NS + g] + (int)eidx[e];
    cw[pos] = make_int2(c, __float_as_int(w));
  }
}

// ---------------- weight prep ----------------

// WcatT[o][k] bf16, k = seg*128 + i ; seg0 = W0-W2, seg1 = W1, seg2 = 2*W2; blockIdx.y = layer
__global__ void combine_weightsT_kernel(const float* __restrict__ W0,
                                        const float* __restrict__ W1,
                                        const float* __restrict__ W2,
                                        unsigned short* __restrict__ WcatT) {
  int l = blockIdx.y;
  const float* W = (l == 0) ? W0 : (l == 1) ? W1 : W2;
  unsigned short* outp = WcatT + (size_t)l * 128 * 384;
  int idx = blockIdx.x * blockDim.x + threadIdx.x;
  if (idx < DIM * DIM) {
    int i = idx >> 7, o = idx & 127;
    float w0 = W[i * DIM + o];
    float w1 = W[DIM * DIM + i * DIM + o];
    float w2 = W[2 * DIM * DIM + i * DIM + o];
    outp[(size_t)o * 384 + i] = f2bf(w0 - w2);
    outp[(size_t)o * 384 + 128 + i] = f2bf(w1);
    outp[(size_t)o * 384 + 256 + i] = f2bf(2.0f * w2);
  }
}

__global__ void wc1t_kernel(const float* __restrict__ Wc1, unsigned short* __restrict__ Wc1T) {
  int idx = blockIdx.x * blockDim.x + threadIdx.x;
  if (idx < 128 * 256) {
    int k = idx >> 8, n = idx & 255;
    Wc1T[(size_t)n * 128 + k] = f2bf(Wc1[(size_t)k * 256 + n]);
  }
}

__global__ void f2bf_kernel(const float* __restrict__ in, unsigned short* __restrict__ outp,
                            int n4) {
  int i = blockIdx.x * blockDim.x + threadIdx.x;
  if (i < n4) {
    float4 v = reinterpret_cast<const float4*>(in)[i];
    ushort4 o;
    o.x = f2bf(v.x); o.y = f2bf(v.y); o.z = f2bf(v.z); o.w = f2bf(v.w);
    reinterpret_cast<ushort4*>(outp)[i] = o;
  }
}

// ---------------- SpMM: Y = L_hat @ X (bf16 in/out, fp32 accum, 8-way MLP) ----------------

__global__ __launch_bounds__(256) void spmm_kernel(const int* __restrict__ row_ptr,
                                                   const int2* __restrict__ cw,
                                                   const unsigned short* __restrict__ X,
                                                   unsigned short* __restrict__ Y, int N) {
  int row = (blockIdx.x * blockDim.x + threadIdx.x) >> 6;
  int lane = threadIdx.x & 63;
  if (row >= N) return;
  int s = row_ptr[row], e = row_ptr[row + 1];
  float lo0 = 0.f, lo1 = 0.f, lo2 = 0.f, lo3 = 0.f, lo4 = 0.f, lo5 = 0.f, lo6 = 0.f, lo7 = 0.f;
  float hi0 = 0.f, hi1 = 0.f, hi2 = 0.f, hi3 = 0.f, hi4 = 0.f, hi5 = 0.f, hi6 = 0.f, hi7 = 0.f;
  int j = s;
  int lo2b = lane * 2;
  for (; j + 7 < e; j += 8) {
    int2 e0 = cw[j], e1 = cw[j + 1], e2 = cw[j + 2], e3 = cw[j + 3];
    int2 e4 = cw[j + 4], e5 = cw[j + 5], e6 = cw[j + 6], e7 = cw[j + 7];
    unsigned v0 = *reinterpret_cast<const unsigned*>(X + (size_t)e0.x * DIM + lo2b);
    unsigned v1 = *reinterpret_cast<const unsigned*>(X + (size_t)e1.x * DIM + lo2b);
    unsigned v2 = *reinterpret_cast<const unsigned*>(X + (size_t)e2.x * DIM + lo2b);
    unsigned v3 = *reinterpret_cast<const unsigned*>(X + (size_t)e3.x * DIM + lo2b);
    unsigned v4 = *reinterpret_cast<const unsigned*>(X + (size_t)e4.x * DIM + lo2b);
    unsigned v5 = *reinterpret_cast<const unsigned*>(X + (size_t)e5.x * DIM + lo2b);
    unsigned v6 = *reinterpret_cast<const unsigned*>(X + (size_t)e6.x * DIM + lo2b);
    unsigned v7 = *reinterpret_cast<const unsigned*>(X + (size_t)e7.x * DIM + lo2b);
    float w0 = __int_as_float(e0.y), w1 = __int_as_float(e1.y);
    float w2 = __int_as_float(e2.y), w3 = __int_as_float(e3.y);
    float w4 = __int_as_float(e4.y), w5 = __int_as_float(e5.y);
    float w6 = __int_as_float(e6.y), w7 = __int_as_float(e7.y);
    lo0 += w0 * bf2f(v0 & 0xffffu); hi0 += w0 * bf2f(v0 >> 16);
    lo1 += w1 * bf2f(v1 & 0xffffu); hi1 += w1 * bf2f(v1 >> 16);
    lo2 += w2 * bf2f(v2 & 0xffffu); hi2 += w2 * bf2f(v2 >> 16);
    lo3 += w3 * bf2f(v3 & 0xffffu); hi3 += w3 * bf2f(v3 >> 16);
    lo4 += w4 * bf2f(v4 & 0xffffu); hi4 += w4 * bf2f(v4 >> 16);
    lo5 += w5 * bf2f(v5 & 0xffffu); hi5 += w5 * bf2f(v5 >> 16);
    lo6 += w6 * bf2f(v6 & 0xffffu); hi6 += w6 * bf2f(v6 >> 16);
    lo7 += w7 * bf2f(v7 & 0xffffu); hi7 += w7 * bf2f(v7 >> 16);
  }
  for (; j + 1 < e; j += 2) {
    int2 e0 = cw[j], e1 = cw[j + 1];
    unsigned v0 = *reinterpret_cast<const unsigned*>(X + (size_t)e0.x * DIM + lo2b);
    unsigned v1 = *reinterpret_cast<const unsigned*>(X + (size_t)e1.x * DIM + lo2b);
    float w0 = __int_as_float(e0.y), w1 = __int_as_float(e1.y);
    lo0 += w0 * bf2f(v0 & 0xffffu); hi0 += w0 * bf2f(v0 >> 16);
    lo1 += w1 * bf2f(v1 & 0xffffu); hi1 += w1 * bf2f(v1 >> 16);
  }
  if (j < e) {
    int2 e0 = cw[j];
    unsigned v0 = *reinterpret_cast<const unsigned*>(X + (size_t)e0.x * DIM + lo2b);
    float w0 = __int_as_float(e0.y);
    lo0 += w0 * bf2f(v0 & 0xffffu);
    hi0 += w0 * bf2f(v0 >> 16);
  }
  float a0 = ((lo0 + lo1) + (lo2 + lo3)) + ((lo4 + lo5) + (lo6 + lo7));
  float a1 = ((hi0 + hi1) + (hi2 + hi3)) + ((hi4 + hi5) + (hi6 + hi7));
  unsigned o = (unsigned)f2bf(a0) | ((unsigned)f2bf(a1) << 16);
  *reinterpret_cast<unsigned*>(Y + (size_t)row * DIM + lo2b) = o;
}

// ---------------- layer GEMM (MFMA): out = relu(X@(W0-W2) + S1@W1 + S2@(2W2)) ----------------

__global__ __launch_bounds__(256) void gemm3_mfma_kernel(const unsigned short* __restrict__ X,
                                                         const unsigned short* __restrict__ S1,
                                                         const unsigned short* __restrict__ S2,
                                                         const unsigned short* __restrict__ BT,
                                                         unsigned short* __restrict__ out, int M) {
  __shared__ short As[128 * 40];
  __shared__ short Bs[128 * 40];
  int tid = threadIdx.x;
  int wv = tid >> 6, ln = tid & 63;
  int lg = ln >> 4, lr = ln & 15;
  int blockRow = blockIdx.x * 128;
  f32x4 acc[2][8];
#pragma unroll
  for (int m = 0; m < 2; ++m)
#pragma unroll
    for (int n = 0; n < 8; ++n) acc[m][n] = (f32x4){0.f, 0.f, 0.f, 0.f};
  const unsigned short* srcs[3] = {X, S1, S2};
  int srow = tid >> 1;
  int scol = (tid & 1) * 16;
  int arow = blockRow + srow;
  bool aok = arow < M;
  for (int seg = 0; seg < 3; ++seg) {
    const unsigned short* src = srcs[seg];
    for (int k0 = 0; k0 < DIM; k0 += 32) {
      float4 av0, av1;
      if (aok) {
        const float4* ap = reinterpret_cast<const float4*>(src + (size_t)arow * DIM + k0 + scol);
        av0 = ap[0];
        av1 = ap[1];
      } else {
        av0 = make_float4(0.f, 0.f, 0.f, 0.f);
        av1 = av0;
      }
      const float4* bp =
          reinterpret_cast<const float4*>(BT + (size_t)srow * 384 + seg * DIM + k0 + scol);
      float4 bv0 = bp[0], bv1 = bp[1];
      __syncthreads();
      *reinterpret_cast<float4*>(&As[srow * 40 + scol]) = av0;
      *reinterpret_cast<float4*>(&As[srow * 40 + scol + 8]) = av1;
      *reinterpret_cast<float4*>(&Bs[srow * 40 + scol]) = bv0;
      *reinterpret_cast<float4*>(&Bs[srow * 40 + scol + 8]) = bv1;
      __syncthreads();
      bf16x8 af[2], bf[8];
#pragma unroll
      for (int m = 0; m < 2; ++m)
        af[m] = *reinterpret_cast<const bf16x8*>(&As[(wv * 32 + m * 16 + lr) * 40 + lg * 8]);
#pragma unroll
      for (int n = 0; n < 8; ++n)
        bf[n] = *reinterpret_cast<const bf16x8*>(&Bs[(n * 16 + lr) * 40 + lg * 8]);
#pragma unroll
      for (int m = 0; m < 2; ++m)
#pragma unroll
        for (int n = 0; n < 8; ++n)
          acc[m][n] = __builtin_amdgcn_mfma_f32_16x16x32_bf16(af[m], bf[n], acc[m][n], 0, 0, 0);
    }
  }
#pragma unroll
  for (int m = 0; m < 2; ++m)
#pragma unroll
    for (int n = 0; n < 8; ++n) {
      int col = n * 16 + lr;
#pragma unroll
      for (int r = 0; r < 4; ++r) {
        int grow = blockRow + wv * 32 + m * 16 + lg * 4 + r;
        if (grow < M) out[(size_t)grow * DIM + col] = f2bf(fmaxf(acc[m][n][r], 0.f));
      }
    }
}

// ---------------- head GEMM (MFMA): h = relu(X@Wc1 + bc1), bf16 out + fused BN stats ----------------

__global__ __launch_bounds__(256) void head_mfma_kernel(const unsigned short* __restrict__ X,
                                                        const unsigned short* __restrict__ BT,
                                                        const float* __restrict__ bc1,
                                                        unsigned short* __restrict__ h,
                                                        float* __restrict__ sums, int M) {
  __shared__ short As[128 * 40];
  __shared__ short Bs[128 * 40];
  int tid = threadIdx.x;
  int wv = tid >> 6, ln = tid & 63;
  int lg = ln >> 4, lr = ln & 15;
  int blockRow = blockIdx.x * 128;
  int n0 = blockIdx.y * 128;
  f32x4 acc[2][8];
#pragma unroll
  for (int m = 0; m < 2; ++m)
#pragma unroll
    for (int n = 0; n < 8; ++n) acc[m][n] = (f32x4){0.f, 0.f, 0.f, 0.f};
  int srow = tid >> 1;
  int scol = (tid & 1) * 16;
  int arow = blockRow + srow;
  bool aok = arow < M;
  for (int k0 = 0; k0 < DIM; k0 += 32) {
    float4 av0, av1;
    if (aok) {
      const float4* ap = reinterpret_cast<const float4*>(X + (size_t)arow * DIM + k0 + scol);
      av0 = ap[0];
      av1 = ap[1];
    } else {
      av0 = make_float4(0.f, 0.f, 0.f, 0.f);
      av1 = av0;
    }
    const float4* bp =
        reinterpret_cast<const float4*>(BT + (size_t)(n0 + srow) * DIM + k0 + scol);
    float4 bv0 = bp[0], bv1 = bp[1];
    __syncthreads();
    *reinterpret_cast<float4*>(&As[srow * 40 + scol]) = av0;
    *reinterpret_cast<float4*>(&As[srow * 40 + scol + 8]) = av1;
    *reinterpret_cast<float4*>(&Bs[srow * 40 + scol]) = bv0;
    *reinterpret_cast<float4*>(&Bs[srow * 40 + scol + 8]) = bv1;
    __syncthreads();
    bf16x8 af[2], bf[8];
#pragma unroll
    for (int m = 0; m < 2; ++m)
      af[m] = *reinterpret_cast<const bf16x8*>(&As[(wv * 32 + m * 16 + lr) * 40 + lg * 8]);
#pragma unroll
    for (int n = 0; n < 8; ++n)
      bf[n] = *reinterpret_cast<const bf16x8*>(&Bs[(n * 16 + lr) * 40 + lg * 8]);
#pragma unroll
    for (int m = 0; m < 2; ++m)
#pragma unroll
      for (int n = 0; n < 8; ++n)
        acc[m][n] = __builtin_amdgcn_mfma_f32_16x16x32_bf16(af[m], bf[n], acc[m][n], 0, 0, 0);
  }
  float psum[8], psq[8];
#pragma unroll
  for (int n = 0; n < 8; ++n) { psum[n] = 0.f; psq[n] = 0.f; }
#pragma unroll
  for (int m = 0; m < 2; ++m)
#pragma unroll
    for (int n = 0; n < 8; ++n) {
      int colg = n0 + n * 16 + lr;
      float bias = bc1[colg];
#pragma unroll
      for (int r = 0; r < 4; ++r) {
        int grow = blockRow + wv * 32 + m * 16 + lg * 4 + r;
        if (grow < M) {
          float v = fmaxf(acc[m][n][r] + bias, 0.f);
          h[(size_t)grow * 256 + colg] = f2bf(v);
          psum[n] += v;
          psq[n] += v * v;
        }
      }
    }
  float* Rs = reinterpret_cast<float*>(As);
  int rid = wv * 4 + lg;
  __syncthreads();
#pragma unroll
  for (int n = 0; n < 8; ++n) Rs[rid * 128 + n * 16 + lr] = psum[n];
  __syncthreads();
  if (tid < 128) {
    float s = 0.f;
#pragma unroll
    for (int r = 0; r < 16; ++r) s += Rs[r * 128 + tid];
    atomicAdd(&sums[n0 + tid], s);
  }
  __syncthreads();
#pragma unroll
  for (int n = 0; n < 8; ++n) Rs[rid * 128 + n * 16 + lr] = psq[n];
  __syncthreads();
  if (tid < 128) {
    float s = 0.f;
#pragma unroll
    for (int r = 0; r < 16; ++r) s += Rs[r * 128 + tid];
    atomicAdd(&sums[256 + n0 + tid], s);
  }
}

__global__ __launch_bounds__(256) void bnfold_kernel(const float* __restrict__ sums,
                                                     const float* __restrict__ gamma,
                                                     const float* __restrict__ beta,
                                                     const float* __restrict__ Wc2,
                                                     const float* __restrict__ bc2,
                                                     float* __restrict__ W2e,
                                                     float* __restrict__ b2e, int M) {
  __shared__ float bsh[256];
  int c = threadIdx.x;
  float mean = sums[c] / (float)M;
  float var = sums[256 + c] / (float)M - mean * mean;
  float a = gamma[c] * rsqrtf(var + BN_EPS);
  float b = beta[c] - mean * a;
  for (int j = 0; j < 10; ++j) W2e[c * 10 + j] = a * Wc2[c * 10 + j];
  bsh[c] = b;
  __syncthreads();
  if (c < 10) {
    float t = bc2[c];
    for (int k = 0; k < 256; ++k) t += bsh[k] * Wc2[k * 10 + c];
    b2e[c] = t;
  }
}

// ---------------- final: logit = h @ W2e + b2e (one wave per row) ----------------

__global__ __launch_bounds__(256) void final_kernel(const unsigned short* __restrict__ h,
                                                    const float* __restrict__ W2e,
                                                    const float* __restrict__ b2e,
                                                    float* __restrict__ out, int M) {
  __shared__ float Ws[2560];
  __shared__ float bs[10];
  for (int i = threadIdx.x; i < 2560; i += 256) Ws[i] = W2e[i];
  if (threadIdx.x < 10) bs[threadIdx.x] = b2e[threadIdx.x];
  __syncthreads();
  int row = (blockIdx.x * blockDim.x + threadIdx.x) >> 6;
  int lane = threadIdx.x & 63;
  if (row >= M) return;
  uint2 hv = *reinterpret_cast<const uint2*>(h + (size_t)row * 256 + lane * 4);
  float hvv[4] = {bf2f(hv.x & 0xffffu), bf2f(hv.x >> 16), bf2f(hv.y & 0xffffu), bf2f(hv.y >> 16)};
  float p[10];
#pragma unroll
  for (int j = 0; j < 10; ++j) p[j] = 0.f;
#pragma unroll
  for (int t = 0; t < 4; ++t) {
    const float* wrow = &Ws[(lane * 4 + t) * 10];
#pragma unroll
    for (int j = 0; j < 10; ++j) p[j] += hvv[t] * wrow[j];
  }
#pragma unroll
  for (int off = 32; off > 0; off >>= 1)
#pragma unroll
    for (int j = 0; j < 10; ++j) p[j] += __shfl_down(p[j], off);
  if (lane == 0) {
#pragma unroll
    for (int j = 0; j < 10; ++j) out[(size_t)row * 10 + j] = p[j] + bs[j];
  }
}

__global__ void copy4_kernel(const float* __restrict__ src, float* __restrict__ dst, int n) {
  int i = blockIdx.x * blockDim.x + threadIdx.x;
  int i4 = i * 4;
  if (i4 + 3 < n) {
    reinterpret_cast<float4*>(dst)[i] = reinterpret_cast<const float4*>(src)[i];
  } else {
    for (int k = i4; k < n; ++k) dst[k] = src[k];
  }
}

// ---------------- launch ----------------

extern "C" void kernel_launch(void* const* d_in, const int* in_sizes, int n_in,
                              void* d_out, int out_size, void* d_ws, size_t ws_size,
                              hipStream_t stream) {
  const float* features = (const float*)d_in[0];
  const int* ei = (const int*)d_in[1];
  const float* ew = (const float*)d_in[2];
  const float* W0 = (const float*)d_in[3];
  const float* W1 = (const float*)d_in[4];
  const float* W2 = (const float*)d_in[5];
  const float* Wc1 = (const float*)d_in[6];
  const float* bc1 = (const float*)d_in[7];
  const float* gamma = (const float*)d_in[8];
  const float* beta = (const float*)d_in[9];
  const float* Wc2 = (const float*)d_in[10];
  const float* bc2 = (const float*)d_in[11];
  float* out = (float*)d_out;

  const int N = in_sizes[0] / DIM;
  const int E = in_sizes[2];
  const int n8 = N * NS;

  size_t off = 0;
  auto alloc = [&](size_t bytes) -> void* {
    void* p = (char*)d_ws + off;
    off += (bytes + 511) & ~(size_t)511;
    return p;
  };
  float* dinv = (float*)alloc((size_t)N * 4);
  unsigned long long* pck = (unsigned long long*)alloc((size_t)n8 * 8);
  unsigned* eidx = (unsigned*)alloc((size_t)E * 4);
  int* off2 = (int*)alloc((size_t)(n8 + NS) * 4);
  int* bsums = (int*)alloc(1024 * 4);
  int* row_ptr = (int*)alloc((size_t)(N + 1) * 4);
  int2* cw = (int2*)alloc((size_t)E * 8);
  unsigned short* featbf = (unsigned short*)alloc((size_t)N * DIM * 2);
  unsigned short* xbuf = (unsigned short*)alloc((size_t)N * DIM * 2);
  unsigned short* S1 = (unsigned short*)alloc((size_t)N * DIM * 2);
  unsigned short* S2 = (unsigned short*)alloc((size_t)N * DIM * 2);
  unsigned short* h = (unsigned short*)alloc((size_t)N * 256 * 2);
  unsigned short* WcatT = (unsigned short*)alloc((size_t)3 * 128 * 384 * 2);
  unsigned short* Wc1T = (unsigned short*)alloc((size_t)256 * 128 * 2);
  float* W2e = (float*)alloc(2560 * 4);
  float* b2e = (float*)alloc(16 * 4);
  float* sums = (float*)alloc(512 * 4);

  hipMemsetAsync(pck, 0, (size_t)n8 * 8, stream);
  hipMemsetAsync(sums, 0, 512 * 4, stream);

  int eb = (E + 255) / 256;
  int nb = (N + 255) / 256;
  int sa_blocks = (n8 + 511) / 512;

  f2bf_kernel<<<(N * DIM / 4 + 255) / 256, 256, 0, stream>>>(features, featbf, N * DIM / 4);
  deg_hist_kernel<<<eb, 256, 0, stream>>>(ei, ew, pck, eidx, E, N);
  reduce_dinv_kernel<<<nb, 256, 0, stream>>>(pck, dinv, N);
  scan_a_kernel<<<sa_blocks, 512, 0, stream>>>(pck, off2, bsums, n8, N);
  scan_b_kernel<<<1, 1024, 0, stream>>>(bsums, sa_blocks);
  scan_c_kernel<<<sa_blocks, 512, 0, stream>>>(off2, bsums, row_ptr, n8, N, E);
  scatter_kernel<<<eb, 256, 0, stream>>>(ei, ew, dinv, off2, eidx, cw, E, N);

  dim3 cwgrid((DIM * DIM + 255) / 256, 3);
  combine_weightsT_kernel<<<cwgrid, 256, 0, stream>>>(W0, W1, W2, WcatT);
  wc1t_kernel<<<(128 * 256 + 255) / 256, 256, 0, stream>>>(Wc1, Wc1T);

  int spmm_blocks = (N + 3) / 4;
  int gemm_blocks = (N + 127) / 128;
  for (int l = 0; l < 3; ++l) {
    const unsigned short* X = (l == 0) ? featbf : xbuf;
    spmm_kernel<<<spmm_blocks, 256, 0, stream>>>(row_ptr, cw, X, S1, N);
    spmm_kernel<<<spmm_blocks, 256, 0, stream>>>(row_ptr, cw, S1, S2, N);
    gemm3_mfma_kernel<<<gemm_blocks, 256, 0, stream>>>(X, S1, S2, WcatT + (size_t)l * 128 * 384,
                                                       xbuf, N);
  }

  dim3 hgrid(gemm_blocks, 2);
  head_mfma_kernel<<<hgrid, 256, 0, stream>>>(xbuf, Wc1T, bc1, h, sums, N);
  bnfold_kernel<<<1, 256, 0, stream>>>(sums, gamma, beta, Wc2, bc2, W2e, b2e, N);
  final_kernel<<<(N + 3) / 4, 256, 0, stream>>>(h, W2e, b2e, out, N);
  copy4_kernel<<<(E / 4 + 255) / 256, 256, 0, stream>>>(ew, out + (size_t)N * 10, E);
}

// Round 6
// 404.583 us; speedup vs baseline: 2.8003x; 1.0812x over previous
//
#include <hip/hip_runtime.h>
#include <cstdint>
#include <cstddef>

#define DIM 128
#define BN_EPS 1e-5f
#define NS 8  // shards (round-robin blockIdx -> XCD)
#define FIX_SCALE 16777216.0f  // 2^24

typedef short bf16x8 __attribute__((ext_vector_type(8)));
typedef float f32x4 __attribute__((ext_vector_type(4)));

__device__ __forceinline__ unsigned short f2bf(float f) {
  unsigned u = __float_as_uint(f);
  u = (u + 0x7fffu + ((u >> 16) & 1u)) >> 16;
  return (unsigned short)u;
}
__device__ __forceinline__ float bf2f(unsigned v) {  // low 16 bits
  return __uint_as_float(v << 16);
}

// ---------------- preprocessing ----------------

// One packed u64 atomic per edge: high32 = count, low32 = sum of fix24(ew).
// Returned old high word = this edge's rank within its (row,shard) segment.
__global__ void deg_hist_kernel(const int* __restrict__ ei, const float* __restrict__ ew,
                                unsigned long long* __restrict__ pck,
                                unsigned* __restrict__ eidx, int E, int N) {
  int e = blockIdx.x * blockDim.x + threadIdx.x;
  int g = blockIdx.x & (NS - 1);
  if (e < E) {
    int r = ei[e];
    unsigned fix = (unsigned)(ew[e] * FIX_SCALE + 0.5f);
    unsigned long long old =
        atomicAdd(&pck[(size_t)g * N + r], (1ull << 32) | (unsigned long long)fix);
    eidx[e] = (unsigned)(old >> 32);
  }
}

// deg = (sum over shards of low32) * 2^-24 ; dinv = rsqrt
__global__ void reduce_dinv_kernel(const unsigned long long* __restrict__ pck,
                                   float* __restrict__ dinv, int N) {
  int i = blockIdx.x * blockDim.x + threadIdx.x;
  if (i < N) {
    float d = 0.f;
#pragma unroll
    for (int g = 0; g < NS; ++g)
      d += (float)(unsigned)(pck[(size_t)g * N + i] & 0xffffffffull);
    d *= (1.0f / FIX_SCALE);
    dinv[i] = d > 0.f ? rsqrtf(fmaxf(d, 1e-30f)) : 0.f;
  }
}

// scan over 8N counts (row-major, shard-minor) -> off2[r*8+g]
__global__ __launch_bounds__(512) void scan_a_kernel(const unsigned long long* __restrict__ pck,
                                                     int* __restrict__ off2,
                                                     int* __restrict__ bsums, int n8, int N) {
  __shared__ int sd[512];
  int t = threadIdx.x;
  int i = blockIdx.x * 512 + t;
  int v = 0;
  if (i < n8) {
    int g = i & (NS - 1), r = i >> 3;
    v = (int)(pck[(size_t)g * N + r] >> 32);
  }
  sd[t] = v;
  __syncthreads();
  for (int off = 1; off < 512; off <<= 1) {
    int x = (t >= off) ? sd[t - off] : 0;
    __syncthreads();
    sd[t] += x;
    __syncthreads();
  }
  if (i < n8) off2[i] = sd[t] - v;
  if (t == 511) bsums[blockIdx.x] = sd[511];
}

__global__ __launch_bounds__(1024) void scan_b_kernel(int* __restrict__ bsums, int nb) {
  __shared__ int sd[1024];
  int t = threadIdx.x;
  int v = (t < nb) ? bsums[t] : 0;
  sd[t] = v;
  __syncthreads();
  for (int off = 1; off < 1024; off <<= 1) {
    int x = (t >= off) ? sd[t - off] : 0;
    __syncthreads();
    sd[t] += x;
    __syncthreads();
  }
  if (t < nb) bsums[t] = sd[t] - v;  // exclusive
}

// add block offsets; also emit row_ptr (every 8th element) and row_ptr[N]=E
__global__ __launch_bounds__(512) void scan_c_kernel(int* __restrict__ off2,
                                                     const int* __restrict__ bsums,
                                                     int* __restrict__ row_ptr, int n8, int N,
                                                     int E) {
  int i = blockIdx.x * 512 + threadIdx.x;
  if (i < n8) {
    int v = off2[i] + bsums[blockIdx.x];
    off2[i] = v;
    if ((i & (NS - 1)) == 0) row_ptr[i >> 3] = v;
  }
  if (blockIdx.x == 0 && threadIdx.x == 0) row_ptr[N] = E;
}

// atomic-free scatter: pos = off2[r*8+g] + eidx[e]  (same grid/g mapping as deg_hist)
__global__ void scatter_kernel(const int* __restrict__ ei, const float* __restrict__ ew,
                               const float* __restrict__ dinv, const int* __restrict__ off2,
                               const unsigned* __restrict__ eidx, int2* __restrict__ cw, int E,
                               int N) {
  int e = blockIdx.x * blockDim.x + threadIdx.x;
  int g = blockIdx.x & (NS - 1);
  if (e < E) {
    int r = ei[e], c = ei[E + e];
    float w = -dinv[r] * ew[e] * dinv[c];
    int pos = off2[r * NS + g] + (int)eidx[e];
    cw[pos] = make_int2(c, __float_as_int(w));
  }
}

// ---------------- weight prep ----------------

// WcatT[o][k] bf16, k = seg*128 + i ; seg0 = W0-W2, seg1 = W1, seg2 = 2*W2; blockIdx.y = layer
__global__ void combine_weightsT_kernel(const float* __restrict__ W0,
                                        const float* __restrict__ W1,
                                        const float* __restrict__ W2,
                                        unsigned short* __restrict__ WcatT) {
  int l = blockIdx.y;
  const float* W = (l == 0) ? W0 : (l == 1) ? W1 : W2;
  unsigned short* outp = WcatT + (size_t)l * 128 * 384;
  int idx = blockIdx.x * blockDim.x + threadIdx.x;
  if (idx < DIM * DIM) {
    int i = idx >> 7, o = idx & 127;
    float w0 = W[i * DIM + o];
    float w1 = W[DIM * DIM + i * DIM + o];
    float w2 = W[2 * DIM * DIM + i * DIM + o];
    outp[(size_t)o * 384 + i] = f2bf(w0 - w2);
    outp[(size_t)o * 384 + 128 + i] = f2bf(w1);
    outp[(size_t)o * 384 + 256 + i] = f2bf(2.0f * w2);
  }
}

__global__ void wc1t_kernel(const float* __restrict__ Wc1, unsigned short* __restrict__ Wc1T) {
  int idx = blockIdx.x * blockDim.x + threadIdx.x;
  if (idx < 128 * 256) {
    int k = idx >> 8, n = idx & 255;
    Wc1T[(size_t)n * 128 + k] = f2bf(Wc1[(size_t)k * 256 + n]);
  }
}

__global__ void f2bf_kernel(const float* __restrict__ in, unsigned short* __restrict__ outp,
                            int n4) {
  int i = blockIdx.x * blockDim.x + threadIdx.x;
  if (i < n4) {
    float4 v = reinterpret_cast<const float4*>(in)[i];
    ushort4 o;
    o.x = f2bf(v.x); o.y = f2bf(v.y); o.z = f2bf(v.z); o.w = f2bf(v.w);
    reinterpret_cast<ushort4*>(outp)[i] = o;
  }
}

// ---------------- SpMM: Y = L_hat @ X (bf16, fp32 accum) ----------------
// Wave = 1 row; lane halves process even/odd edges; lane covers 4 cols (uint2 = 8B).

__global__ __launch_bounds__(256) void spmm_kernel(const int* __restrict__ row_ptr,
                                                   const int2* __restrict__ cw,
                                                   const unsigned short* __restrict__ X,
                                                   unsigned short* __restrict__ Y, int N) {
  int row = (blockIdx.x * blockDim.x + threadIdx.x) >> 6;
  int lane = threadIdx.x & 63;
  if (row >= N) return;
  int half = lane >> 5;
  int l32 = lane & 31;
  int cb = l32 * 4;
  int s = row_ptr[row], e = row_ptr[row + 1];
  float a0 = 0.f, a1 = 0.f, a2 = 0.f, a3 = 0.f;
  float b0 = 0.f, b1 = 0.f, b2 = 0.f, b3 = 0.f;
  int j = s + half;
  for (; j + 6 < e; j += 8) {
    int2 e0 = cw[j], e1 = cw[j + 2], e2 = cw[j + 4], e3 = cw[j + 6];
    uint2 v0 = *reinterpret_cast<const uint2*>(X + (size_t)e0.x * DIM + cb);
    uint2 v1 = *reinterpret_cast<const uint2*>(X + (size_t)e1.x * DIM + cb);
    uint2 v2 = *reinterpret_cast<const uint2*>(X + (size_t)e2.x * DIM + cb);
    uint2 v3 = *reinterpret_cast<const uint2*>(X + (size_t)e3.x * DIM + cb);
    float w0 = __int_as_float(e0.y), w1 = __int_as_float(e1.y);
    float w2 = __int_as_float(e2.y), w3 = __int_as_float(e3.y);
    a0 += w0 * bf2f(v0.x & 0xffffu); a1 += w0 * bf2f(v0.x >> 16);
    a2 += w0 * bf2f(v0.y & 0xffffu); a3 += w0 * bf2f(v0.y >> 16);
    b0 += w1 * bf2f(v1.x & 0xffffu); b1 += w1 * bf2f(v1.x >> 16);
    b2 += w1 * bf2f(v1.y & 0xffffu); b3 += w1 * bf2f(v1.y >> 16);
    a0 += w2 * bf2f(v2.x & 0xffffu); a1 += w2 * bf2f(v2.x >> 16);
    a2 += w2 * bf2f(v2.y & 0xffffu); a3 += w2 * bf2f(v2.y >> 16);
    b0 += w3 * bf2f(v3.x & 0xffffu); b1 += w3 * bf2f(v3.x >> 16);
    b2 += w3 * bf2f(v3.y & 0xffffu); b3 += w3 * bf2f(v3.y >> 16);
  }
  for (; j < e; j += 2) {
    int2 e0 = cw[j];
    uint2 v0 = *reinterpret_cast<const uint2*>(X + (size_t)e0.x * DIM + cb);
    float w0 = __int_as_float(e0.y);
    a0 += w0 * bf2f(v0.x & 0xffffu); a1 += w0 * bf2f(v0.x >> 16);
    a2 += w0 * bf2f(v0.y & 0xffffu); a3 += w0 * bf2f(v0.y >> 16);
  }
  a0 += b0; a1 += b1; a2 += b2; a3 += b3;
  a0 += __shfl_xor(a0, 32);
  a1 += __shfl_xor(a1, 32);
  a2 += __shfl_xor(a2, 32);
  a3 += __shfl_xor(a3, 32);
  if (half == 0) {
    uint2 o;
    o.x = (unsigned)f2bf(a0) | ((unsigned)f2bf(a1) << 16);
    o.y = (unsigned)f2bf(a2) | ((unsigned)f2bf(a3) << 16);
    *reinterpret_cast<uint2*>(Y + (size_t)row * DIM + cb) = o;
  }
}

// ---------------- layer GEMM (MFMA): out = relu(X@(W0-W2) + S1@W1 + S2@(2W2)) ----------------

__global__ __launch_bounds__(256) void gemm3_mfma_kernel(const unsigned short* __restrict__ X,
                                                         const unsigned short* __restrict__ S1,
                                                         const unsigned short* __restrict__ S2,
                                                         const unsigned short* __restrict__ BT,
                                                         unsigned short* __restrict__ out, int M) {
  __shared__ short As[128 * 40];
  __shared__ short Bs[128 * 40];
  int tid = threadIdx.x;
  int wv = tid >> 6, ln = tid & 63;
  int lg = ln >> 4, lr = ln & 15;
  int blockRow = blockIdx.x * 128;
  f32x4 acc[2][8];
#pragma unroll
  for (int m = 0; m < 2; ++m)
#pragma unroll
    for (int n = 0; n < 8; ++n) acc[m][n] = (f32x4){0.f, 0.f, 0.f, 0.f};
  const unsigned short* srcs[3] = {X, S1, S2};
  int srow = tid >> 1;
  int scol = (tid & 1) * 16;
  int arow = blockRow + srow;
  bool aok = arow < M;
  for (int seg = 0; seg < 3; ++seg) {
    const unsigned short* src = srcs[seg];
    for (int k0 = 0; k0 < DIM; k0 += 32) {
      float4 av0, av1;
      if (aok) {
        const float4* ap = reinterpret_cast<const float4*>(src + (size_t)arow * DIM + k0 + scol);
        av0 = ap[0];
        av1 = ap[1];
      } else {
        av0 = make_float4(0.f, 0.f, 0.f, 0.f);
        av1 = av0;
      }
      const float4* bp =
          reinterpret_cast<const float4*>(BT + (size_t)srow * 384 + seg * DIM + k0 + scol);
      float4 bv0 = bp[0], bv1 = bp[1];
      __syncthreads();
      *reinterpret_cast<float4*>(&As[srow * 40 + scol]) = av0;
      *reinterpret_cast<float4*>(&As[srow * 40 + scol + 8]) = av1;
      *reinterpret_cast<float4*>(&Bs[srow * 40 + scol]) = bv0;
      *reinterpret_cast<float4*>(&Bs[srow * 40 + scol + 8]) = bv1;
      __syncthreads();
      bf16x8 af[2], bf[8];
#pragma unroll
      for (int m = 0; m < 2; ++m)
        af[m] = *reinterpret_cast<const bf16x8*>(&As[(wv * 32 + m * 16 + lr) * 40 + lg * 8]);
#pragma unroll
      for (int n = 0; n < 8; ++n)
        bf[n] = *reinterpret_cast<const bf16x8*>(&Bs[(n * 16 + lr) * 40 + lg * 8]);
#pragma unroll
      for (int m = 0; m < 2; ++m)
#pragma unroll
        for (int n = 0; n < 8; ++n)
          acc[m][n] = __builtin_amdgcn_mfma_f32_16x16x32_bf16(af[m], bf[n], acc[m][n], 0, 0, 0);
    }
  }
#pragma unroll
  for (int m = 0; m < 2; ++m)
#pragma unroll
    for (int n = 0; n < 8; ++n) {
      int col = n * 16 + lr;
#pragma unroll
      for (int r = 0; r < 4; ++r) {
        int grow = blockRow + wv * 32 + m * 16 + lg * 4 + r;
        if (grow < M) out[(size_t)grow * DIM + col] = f2bf(fmaxf(acc[m][n][r], 0.f));
      }
    }
}

// ---------------- head GEMM (MFMA): h = relu(X@Wc1 + bc1), bf16 out + fused BN stats ----------------

__global__ __launch_bounds__(256) void head_mfma_kernel(const unsigned short* __restrict__ X,
                                                        const unsigned short* __restrict__ BT,
                                                        const float* __restrict__ bc1,
                                                        unsigned short* __restrict__ h,
                                                        float* __restrict__ sums, int M) {
  __shared__ short As[128 * 40];
  __shared__ short Bs[128 * 40];
  int tid = threadIdx.x;
  int wv = tid >> 6, ln = tid & 63;
  int lg = ln >> 4, lr = ln & 15;
  int blockRow = blockIdx.x * 128;
  int n0 = blockIdx.y * 128;
  f32x4 acc[2][8];
#pragma unroll
  for (int m = 0; m < 2; ++m)
#pragma unroll
    for (int n = 0; n < 8; ++n) acc[m][n] = (f32x4){0.f, 0.f, 0.f, 0.f};
  int srow = tid >> 1;
  int scol = (tid & 1) * 16;
  int arow = blockRow + srow;
  bool aok = arow < M;
  for (int k0 = 0; k0 < DIM; k0 += 32) {
    float4 av0, av1;
    if (aok) {
      const float4* ap = reinterpret_cast<const float4*>(X + (size_t)arow * DIM + k0 + scol);
      av0 = ap[0];
      av1 = ap[1];
    } else {
      av0 = make_float4(0.f, 0.f, 0.f, 0.f);
      av1 = av0;
    }
    const float4* bp =
        reinterpret_cast<const float4*>(BT + (size_t)(n0 + srow) * DIM + k0 + scol);
    float4 bv0 = bp[0], bv1 = bp[1];
    __syncthreads();
    *reinterpret_cast<float4*>(&As[srow * 40 + scol]) = av0;
    *reinterpret_cast<float4*>(&As[srow * 40 + scol + 8]) = av1;
    *reinterpret_cast<float4*>(&Bs[srow * 40 + scol]) = bv0;
    *reinterpret_cast<float4*>(&Bs[srow * 40 + scol + 8]) = bv1;
    __syncthreads();
    bf16x8 af[2], bf[8];
#pragma unroll
    for (int m = 0; m < 2; ++m)
      af[m] = *reinterpret_cast<const bf16x8*>(&As[(wv * 32 + m * 16 + lr) * 40 + lg * 8]);
#pragma unroll
    for (int n = 0; n < 8; ++n)
      bf[n] = *reinterpret_cast<const bf16x8*>(&Bs[(n * 16 + lr) * 40 + lg * 8]);
#pragma unroll
    for (int m = 0; m < 2; ++m)
#pragma unroll
      for (int n = 0; n < 8; ++n)
        acc[m][n] = __builtin_amdgcn_mfma_f32_16x16x32_bf16(af[m], bf[n], acc[m][n], 0, 0, 0);
  }
  float psum[8], psq[8];
#pragma unroll
  for (int n = 0; n < 8; ++n) { psum[n] = 0.f; psq[n] = 0.f; }
#pragma unroll
  for (int m = 0; m < 2; ++m)
#pragma unroll
    for (int n = 0; n < 8; ++n) {
      int colg = n0 + n * 16 + lr;
      float bias = bc1[colg];
#pragma unroll
      for (int r = 0; r < 4; ++r) {
        int grow = blockRow + wv * 32 + m * 16 + lg * 4 + r;
        if (grow < M) {
          float v = fmaxf(acc[m][n][r] + bias, 0.f);
          h[(size_t)grow * 256 + colg] = f2bf(v);
          psum[n] += v;
          psq[n] += v * v;
        }
      }
    }
  float* Rs = reinterpret_cast<float*>(As);
  int rid = wv * 4 + lg;
  __syncthreads();
#pragma unroll
  for (int n = 0; n < 8; ++n) Rs[rid * 128 + n * 16 + lr] = psum[n];
  __syncthreads();
  if (tid < 128) {
    float s = 0.f;
#pragma unroll
    for (int r = 0; r < 16; ++r) s += Rs[r * 128 + tid];
    atomicAdd(&sums[n0 + tid], s);
  }
  __syncthreads();
#pragma unroll
  for (int n = 0; n < 8; ++n) Rs[rid * 128 + n * 16 + lr] = psq[n];
  __syncthreads();
  if (tid < 128) {
    float s = 0.f;
#pragma unroll
    for (int r = 0; r < 16; ++r) s += Rs[r * 128 + tid];
    atomicAdd(&sums[256 + n0 + tid], s);
  }
}

__global__ __launch_bounds__(256) void bnfold_kernel(const float* __restrict__ sums,
                                                     const float* __restrict__ gamma,
                                                     const float* __restrict__ beta,
                                                     const float* __restrict__ Wc2,
                                                     const float* __restrict__ bc2,
                                                     float* __restrict__ W2e,
                                                     float* __restrict__ b2e, int M) {
  __shared__ float bsh[256];
  int c = threadIdx.x;
  float mean = sums[c] / (float)M;
  float var = sums[256 + c] / (float)M - mean * mean;
  float a = gamma[c] * rsqrtf(var + BN_EPS);
  float b = beta[c] - mean * a;
  for (int j = 0; j < 10; ++j) W2e[c * 10 + j] = a * Wc2[c * 10 + j];
  bsh[c] = b;
  __syncthreads();
  if (c < 10) {
    float t = bc2[c];
    for (int k = 0; k < 256; ++k) t += bsh[k] * Wc2[k * 10 + c];
    b2e[c] = t;
  }
}

// ---------------- final: logit = h @ W2e + b2e (thread per row, broadcast W) ----------------

__global__ __launch_bounds__(256) void final_kernel(const unsigned short* __restrict__ h,
                                                    const float* __restrict__ W2e,
                                                    const float* __restrict__ b2e,
                                                    float* __restrict__ out, int M) {
  __shared__ float Ws[2560];
  __shared__ float bs[16];
  for (int i = threadIdx.x; i < 2560; i += 256) Ws[i] = W2e[i];
  if (threadIdx.x < 10) bs[threadIdx.x] = b2e[threadIdx.x];
  __syncthreads();
  int row = blockIdx.x * 256 + threadIdx.x;
  if (row >= M) return;
  float p[10];
#pragma unroll
  for (int j = 0; j < 10; ++j) p[j] = bs[j];
  const uint4* hp = reinterpret_cast<const uint4*>(h + (size_t)row * 256);
#pragma unroll 4
  for (int k0 = 0; k0 < 32; ++k0) {
    uint4 v = hp[k0];
    unsigned vv[4] = {v.x, v.y, v.z, v.w};
#pragma unroll
    for (int t = 0; t < 4; ++t) {
      float f0 = bf2f(vv[t] & 0xffffu);
      float f1 = bf2f(vv[t] >> 16);
      const float* w0 = &Ws[(k0 * 8 + t * 2) * 10];  // uniform address -> LDS broadcast
#pragma unroll
      for (int j = 0; j < 10; ++j) p[j] += f0 * w0[j] + f1 * w0[10 + j];
    }
  }
#pragma unroll
  for (int j = 0; j < 10; ++j) out[(size_t)row * 10 + j] = p[j];
}

__global__ void copy4_kernel(const float* __restrict__ src, float* __restrict__ dst, int n) {
  int i = blockIdx.x * blockDim.x + threadIdx.x;
  int i4 = i * 4;
  if (i4 + 3 < n) {
    reinterpret_cast<float4*>(dst)[i] = reinterpret_cast<const float4*>(src)[i];
  } else {
    for (int k = i4; k < n; ++k) dst[k] = src[k];
  }
}

// ---------------- launch ----------------

extern "C" void kernel_launch(void* const* d_in, const int* in_sizes, int n_in,
                              void* d_out, int out_size, void* d_ws, size_t ws_size,
                              hipStream_t stream) {
  const float* features = (const float*)d_in[0];
  const int* ei = (const int*)d_in[1];
  const float* ew = (const float*)d_in[2];
  const float* W0 = (const float*)d_in[3];
  const float* W1 = (const float*)d_in[4];
  const float* W2 = (const float*)d_in[5];
  const float* Wc1 = (const float*)d_in[6];
  const float* bc1 = (const float*)d_in[7];
  const float* gamma = (const float*)d_in[8];
  const float* beta = (const float*)d_in[9];
  const float* Wc2 = (const float*)d_in[10];
  const float* bc2 = (const float*)d_in[11];
  float* out = (float*)d_out;

  const int N = in_sizes[0] / DIM;
  const int E = in_sizes[2];
  const int n8 = N * NS;

  size_t off = 0;
  auto alloc = [&](size_t bytes) -> void* {
    void* p = (char*)d_ws + off;
    off += (bytes + 511) & ~(size_t)511;
    return p;
  };
  float* dinv = (float*)alloc((size_t)N * 4);
  unsigned long long* pck = (unsigned long long*)alloc((size_t)n8 * 8);
  unsigned* eidx = (unsigned*)alloc((size_t)E * 4);
  int* off2 = (int*)alloc((size_t)(n8 + NS) * 4);
  int* bsums = (int*)alloc(1024 * 4);
  int* row_ptr = (int*)alloc((size_t)(N + 1) * 4);
  int2* cw = (int2*)alloc((size_t)E * 8);
  unsigned short* featbf = (unsigned short*)alloc((size_t)N * DIM * 2);
  unsigned short* xbuf = (unsigned short*)alloc((size_t)N * DIM * 2);
  unsigned short* S1 = (unsigned short*)alloc((size_t)N * DIM * 2);
  unsigned short* S2 = (unsigned short*)alloc((size_t)N * DIM * 2);
  unsigned short* h = (unsigned short*)alloc((size_t)N * 256 * 2);
  unsigned short* WcatT = (unsigned short*)alloc((size_t)3 * 128 * 384 * 2);
  unsigned short* Wc1T = (unsigned short*)alloc((size_t)256 * 128 * 2);
  float* W2e = (float*)alloc(2560 * 4);
  float* b2e = (float*)alloc(16 * 4);
  float* sums = (float*)alloc(512 * 4);

  hipMemsetAsync(pck, 0, (size_t)n8 * 8, stream);
  hipMemsetAsync(sums, 0, 512 * 4, stream);

  int eb = (E + 255) / 256;
  int nb = (N + 255) / 256;
  int sa_blocks = (n8 + 511) / 512;

  f2bf_kernel<<<(N * DIM / 4 + 255) / 256, 256, 0, stream>>>(features, featbf, N * DIM / 4);
  deg_hist_kernel<<<eb, 256, 0, stream>>>(ei, ew, pck, eidx, E, N);
  reduce_dinv_kernel<<<nb, 256, 0, stream>>>(pck, dinv, N);
  scan_a_kernel<<<sa_blocks, 512, 0, stream>>>(pck, off2, bsums, n8, N);
  scan_b_kernel<<<1, 1024, 0, stream>>>(bsums, sa_blocks);
  scan_c_kernel<<<sa_blocks, 512, 0, stream>>>(off2, bsums, row_ptr, n8, N, E);
  scatter_kernel<<<eb, 256, 0, stream>>>(ei, ew, dinv, off2, eidx, cw, E, N);

  dim3 cwgrid((DIM * DIM + 255) / 256, 3);
  combine_weightsT_kernel<<<cwgrid, 256, 0, stream>>>(W0, W1, W2, WcatT);
  wc1t_kernel<<<(128 * 256 + 255) / 256, 256, 0, stream>>>(Wc1, Wc1T);

  int spmm_blocks = (N + 3) / 4;
  int gemm_blocks = (N + 127) / 128;
  for (int l = 0; l < 3; ++l) {
    const unsigned short* X = (l == 0) ? featbf : xbuf;
    spmm_kernel<<<spmm_blocks, 256, 0, stream>>>(row_ptr, cw, X, S1, N);
    spmm_kernel<<<spmm_blocks, 256, 0, stream>>>(row_ptr, cw, S1, S2, N);
    gemm3_mfma_kernel<<<gemm_blocks, 256, 0, stream>>>(X, S1, S2, WcatT + (size_t)l * 128 * 384,
                                                       xbuf, N);
  }

  dim3 hgrid(gemm_blocks, 2);
  head_mfma_kernel<<<hgrid, 256, 0, stream>>>(xbuf, Wc1T, bc1, h, sums, N);
  bnfold_kernel<<<1, 256, 0, stream>>>(sums, gamma, beta, Wc2, bc2, W2e, b2e, N);
  final_kernel<<<(N + 255) / 256, 256, 0, stream>>>(h, W2e, b2e, out, N);
  copy4_kernel<<<(E / 4 + 255) / 256, 256, 0, stream>>>(ew, out + (size_t)N * 10, E);
}